// Round 1
// baseline (378.416 us; speedup 1.0000x reference)
//
#include <hip/hip_runtime.h>
#include <hip/hip_fp16.h>

#define EPS 0.1f
#define SINK_ITERS 50
#define KSCALE_LN 9.0109133472f   /* 13*ln2 : K scaled by 2^13 into f16 normal range */

typedef _Float16 f16;
typedef _Float16 f16x2 __attribute__((ext_vector_type(2)));

#ifndef __has_builtin
#define __has_builtin(x) 0
#endif
#if __has_builtin(__builtin_amdgcn_fdot2)
#define HAVE_FDOT2 1
#else
#define HAVE_FDOT2 0
#endif

__device__ __forceinline__ float wave_red_sum(float v) {
    #pragma unroll
    for (int o = 32; o; o >>= 1) v += __shfl_xor(v, o, 64);
    return v;
}

__device__ __forceinline__ float dp2(unsigned kp, unsigned up, float acc) {
#if HAVE_FDOT2
    return __builtin_amdgcn_fdot2(__builtin_bit_cast(f16x2, kp),
                                  __builtin_bit_cast(f16x2, up), acc, false);
#else
    f16x2 k2 = __builtin_bit_cast(f16x2, kp);
    f16x2 u2 = __builtin_bit_cast(f16x2, up);
    acc = fmaf((float)k2.x, (float)u2.x, acc);
    acc = fmaf((float)k2.y, (float)u2.y, acc);
    return acc;
#endif
}

__device__ __forceinline__ float dp8(uint4 kv, uint4 uv, float acc) {
    acc = dp2(kv.x, uv.x, acc);
    acc = dp2(kv.y, uv.y, acc);
    acc = dp2(kv.z, uv.z, acc);
    acc = dp2(kv.w, uv.w, acc);
    return acc;
}

// ---------------- init: zero ws accumulators ----------------
__global__ void k_init(float* acc) {
    if (threadIdx.x < 16) acc[threadIdx.x] = 0.f;
}

// ---------------- recon loss: sum (xr-xo)^2 over 256*4096 ----------------
__global__ __launch_bounds__(256) void k_recon(const float* __restrict__ xo,
                                               const float* __restrict__ xr,
                                               float* __restrict__ acc) {
    __shared__ float red[4];
    int tid = blockIdx.x * 256 + threadIdx.x;
    float s = 0.f;
    for (int i = tid; i < 256 * 4096; i += gridDim.x * 256) {
        float d = xr[i] - xo[i];
        s = fmaf(d, d, s);
    }
    s = wave_red_sum(s);
    if ((threadIdx.x & 63) == 0) red[threadIdx.x >> 6] = s;
    __syncthreads();
    if (threadIdx.x == 0) atomicAdd(acc, red[0] + red[1] + red[2] + red[3]);
}

// ---------------- row-normalize: xn = x / sqrt(max(sum x^2,1e-8)) ----------------
__global__ __launch_bounds__(256) void k_normalize(const float* __restrict__ x,
                                                   float* __restrict__ xn, int cols) {
    __shared__ float red[4];
    int row = blockIdx.x;
    float s = 0.f;
    for (int c = threadIdx.x; c < cols; c += 256) {
        float v = x[row * cols + c];
        s = fmaf(v, v, s);
    }
    s = wave_red_sum(s);
    if ((threadIdx.x & 63) == 0) red[threadIdx.x >> 6] = s;
    __syncthreads();
    float tot = red[0] + red[1] + red[2] + red[3];
    float rn = 1.f / sqrtf(fmaxf(tot, 1e-8f));
    for (int c = threadIdx.x; c < cols; c += 256) {
        xn[row * cols + c] = x[row * cols + c] * rn;
    }
}

// ---------------- GEMM: partial[slab] = A_tile @ A_tile^T over 256-wide k slab ----------------
// grid (4,4,slabs), block 256. 64x64 tile, 4x4 micro-tile.
__global__ __launch_bounds__(256) void k_gemm_aat(const float* __restrict__ A, int lda,
                                                  float* __restrict__ part) {
    __shared__ float At[64][17], Bt[64][17];
    int i0 = blockIdx.x * 64, j0 = blockIdx.y * 64, k0 = blockIdx.z * 256;
    int t = threadIdx.x, tx = t & 15, ty = t >> 4;
    float acc[4][4] = {};
    for (int kc = 0; kc < 256; kc += 16) {
        __syncthreads();
        #pragma unroll
        for (int m = 0; m < 4; m++) {
            int idx = m * 256 + t;
            int kk = idx & 15, row = idx >> 4;
            At[row][kk] = A[(size_t)(i0 + row) * lda + k0 + kc + kk];
            Bt[row][kk] = A[(size_t)(j0 + row) * lda + k0 + kc + kk];
        }
        __syncthreads();
        #pragma unroll
        for (int kk = 0; kk < 16; kk++) {
            float a[4], b[4];
            #pragma unroll
            for (int m = 0; m < 4; m++) a[m] = At[ty * 4 + m][kk];
            #pragma unroll
            for (int n = 0; n < 4; n++) b[n] = Bt[tx * 4 + n][kk];
            #pragma unroll
            for (int m = 0; m < 4; m++)
                #pragma unroll
                for (int n = 0; n < 4; n++)
                    acc[m][n] = fmaf(a[m], b[n], acc[m][n]);
        }
    }
    #pragma unroll
    for (int m = 0; m < 4; m++) {
        float4 v = make_float4(acc[m][0], acc[m][1], acc[m][2], acc[m][3]);
        *(float4*)&part[(size_t)blockIdx.z * 65536 + (i0 + ty * 4 + m) * 256 + j0 + tx * 4] = v;
    }
}

// ---------------- D = clip(1 - sum_slabs partial, 0) ----------------
__global__ __launch_bounds__(256) void k_reduce_d(const float* __restrict__ part, int nslab,
                                                  float* __restrict__ D) {
    int e = blockIdx.x * 256 + threadIdx.x;
    float s = 0.f;
    for (int sl = 0; sl < nslab; sl++) s += part[(size_t)sl * 65536 + e];
    float v = 1.f - s;
    D[e] = v > 0.f ? v : 0.f;
}

// ---------------- exact median of 65536 non-negative floats ----------------
// uint-bitpattern bisection; single block of 1024 threads, data in registers.
__global__ __launch_bounds__(1024) void k_median(const float* __restrict__ D,
                                                 float* __restrict__ out_sigma) {
    __shared__ int redc[16];
    unsigned r[64];
    int t = threadIdx.x;
    #pragma unroll
    for (int i = 0; i < 64; i++) r[i] = __float_as_uint(D[t + i * 1024]);
    unsigned res[2];
    for (int sel = 0; sel < 2; sel++) {
        int k = 32767 + sel;
        unsigned lo = 0u, hi = 0x7F800000u;  // count_less(lo)=0 <= k < 65536 = count_less(hi)
        while (hi - lo > 1u) {
            unsigned mid = (lo + hi) >> 1;
            int c = 0;
            #pragma unroll
            for (int i = 0; i < 64; i++) c += (r[i] < mid) ? 1 : 0;
            #pragma unroll
            for (int o = 32; o; o >>= 1) c += __shfl_xor(c, o, 64);
            if ((t & 63) == 0) redc[t >> 6] = c;
            __syncthreads();
            int tot = 0;
            for (int w = 0; w < 16; w++) tot += redc[w];
            if (tot <= k) lo = mid; else hi = mid;
            __syncthreads();
        }
        res[sel] = lo;
    }
    if (t == 0)
        out_sigma[0] = 0.5f * (__uint_as_float(res[0]) + __uint_as_float(res[1]));
}

// ---------------- prep: S, P, EPS*logP, and scaled f16 kernel K ----------------
__global__ __launch_bounds__(256) void k_prep(const float* __restrict__ Do,
                                              const float* __restrict__ Dl,
                                              const float* __restrict__ wsacc,
                                              const float* __restrict__ lsl,
                                              float* __restrict__ Po, float* __restrict__ Pl,
                                              float* __restrict__ ELo, float* __restrict__ ELl,
                                              f16* __restrict__ Kh) {
    __shared__ float red[8];
    int i = blockIdx.x, j = threadIdx.x;
    float sig_o = wsacc[4];
    if (sig_o == 0.f) sig_o = 1e-6f;
    float x = lsl[0];
    float sp = (x > 20.f) ? x : log1pf(__expf(x));
    float sig_l = sp + 1e-6f;
    float i2o = 1.f / (2.f * sig_o * sig_o);
    float i2l = 1.f / (2.f * sig_l * sig_l);
    float d_o = Do[i * 256 + j], d_l = Dl[i * 256 + j];
    float so = (i == j) ? 0.f : __expf(-d_o * d_o * i2o);
    float sl = (i == j) ? 0.f : __expf(-d_l * d_l * i2l);
    float wso = wave_red_sum(so);
    float wsl = wave_red_sum(sl);
    if ((j & 63) == 0) { red[j >> 6] = wso; red[4 + (j >> 6)] = wsl; }
    __syncthreads();
    float sum_o = red[0] + red[1] + red[2] + red[3];
    float sum_l = red[4] + red[5] + red[6] + red[7];
    float po = so / fmaxf(sum_o, 1e-8f);
    float pl = sl / fmaxf(sum_l, 1e-8f);
    Po[i * 256 + j] = po;
    Pl[i * 256 + j] = pl;
    ELo[i * 256 + j] = EPS * __logf(fmaxf(po, 1e-8f));
    ELl[i * 256 + j] = EPS * __logf(fmaxf(pl, 1e-8f));
    // K'[k=i][c=j] = exp(-C/eps) * 2^13, packed so column c's k-run is b128-readable:
    // half index = ((k>>3)*256 + c)*8 + (k&7)
    float kv = __expf(-d_o * (1.f / EPS) + KSCALE_LN);
    Kh[(((i >> 3) * 256 + j) << 3) + (i & 7)] = (f16)kv;
}

// ---------------- Sinkhorn: 768 independent row problems, K in registers ----------------
// grid 256 x 512. wg w owns global rows 3w..3w+2 (row r: sinkhorn s=r>>8, batch i=r&255).
__global__ __launch_bounds__(512) void k_sinkhorn(const float* __restrict__ Po,
                                                  const float* __restrict__ Pl,
                                                  const float* __restrict__ ELo,
                                                  const float* __restrict__ ELl,
                                                  const uint4* __restrict__ Kq,
                                                  float* __restrict__ wsacc) {
    __shared__ float F[3][256], G[3][256], ELa[3][256], ELb[3][256];
    __shared__ __align__(16) f16 UH[3][256];
    __shared__ float ZP[3][2][256];
    __shared__ float red[24];
    int t = threadIdx.x, c = t & 255, h = t >> 8;
    int w = blockIdx.x;

    // K fragment: thread (c,h) holds K'[k][c] for k in [h*128, h*128+128) = 16 uint4
    uint4 karr[16];
    #pragma unroll
    for (int s = 0; s < 16; s++) karr[s] = Kq[(h * 16 + s) * 256 + c];

    const float* ELa_p[3];
    const float* ELb_p[3];
    const float* Pa_p[3];
    const float* Pb_p[3];
    #pragma unroll
    for (int q = 0; q < 3; q++) {
        int r = w * 3 + q, s = r >> 8, i = r & 255;
        ELa_p[q] = (s == 1 ? ELl : ELo) + i * 256;  // la from a
        ELb_p[q] = (s == 2 ? ELo : ELl) + i * 256;  // lb from b
        Pa_p[q] = (s == 1 ? Pl : Po) + i * 256;
        Pb_p[q] = (s == 2 ? Po : Pl) + i * 256;
    }
    if (t < 256) {
        #pragma unroll
        for (int q = 0; q < 3; q++) {
            F[q][t] = 0.f; G[q][t] = 0.f;
            ELa[q][t] = ELa_p[q][t];
            ELb[q][t] = ELb_p[q][t];
        }
    }
    __syncthreads();

    for (int it = 0; it < 2 * SINK_ITERS; it++) {
        float(*SRC)[256] = (it & 1) ? G : F;   // g-step reads f; f-step reads g
        float(*DST)[256] = (it & 1) ? F : G;
        float(*ELx)[256] = (it & 1) ? ELa : ELb;
        if (t < 256) {
            #pragma unroll
            for (int q = 0; q < 3; q++) UH[q][t] = (f16)__expf(SRC[q][t]);
        }
        __syncthreads();
        float a0 = 0.f, a1 = 0.f, a2 = 0.f;
        #pragma unroll
        for (int s = 0; s < 16; s++) {
            uint4 kv = karr[s];
            int k2b = h * 64 + s * 4;            // pair index; half index = 2*k2b
            uint4 u0 = *(const uint4*)&UH[0][2 * k2b];
            uint4 u1 = *(const uint4*)&UH[1][2 * k2b];
            uint4 u2 = *(const uint4*)&UH[2][2 * k2b];
            a0 = dp8(kv, u0, a0);
            a1 = dp8(kv, u1, a1);
            a2 = dp8(kv, u2, a2);
        }
        ZP[0][h][c] = a0; ZP[1][h][c] = a1; ZP[2][h][c] = a2;
        __syncthreads();
        for (int idx = t; idx < 768; idx += 512) {
            int q = idx >> 8, cc = idx & 255;
            float z = ZP[q][0][cc] + ZP[q][1][cc];
            DST[q][cc] = ELx[q][cc] - EPS * (__logf(z) - KSCALE_LN);
        }
        __syncthreads();
    }

    // cost_r = sum_k a[k] f[k] + sum_k b[k] g[k]; atomicAdd into ot accumulator per sinkhorn
    float cost[3] = {0.f, 0.f, 0.f};
    if (t < 256) {
        #pragma unroll
        for (int q = 0; q < 3; q++)
            cost[q] = Pa_p[q][t] * F[q][t] + Pb_p[q][t] * G[q][t];
    }
    #pragma unroll
    for (int q = 0; q < 3; q++) {
        float v = wave_red_sum(cost[q]);
        if ((t & 63) == 0) red[(t >> 6) * 3 + q] = v;
    }
    __syncthreads();
    if (t < 3) {
        float s = 0.f;
        for (int wv = 0; wv < 8; wv++) s += red[wv * 3 + t];
        int sdx = (w * 3 + t) >> 8;
        atomicAdd(&wsacc[sdx], s);
    }
}

// ---------------- finalize ----------------
__global__ void k_final(const float* __restrict__ wsacc, const float* __restrict__ lvr_p,
                        const float* __restrict__ lvt_p, float* __restrict__ out) {
    float recon = wsacc[3] * (1.f / (256.f * 4096.f));
    float ot0 = wsacc[0] * (1.f / 256.f);
    float ot1 = wsacc[1] * (1.f / 256.f);
    float ot2 = wsacc[2] * (1.f / 256.f);
    float topo = ot0 - 0.5f * ot1 - 0.5f * ot2;
    topo = topo > 0.f ? topo : 0.f;  // * TOPO_MULT (=1)
    float lvr = lvr_p[0], lvt = lvt_p[0];
    out[0] = 0.5f * __expf(-lvr) * recon + 0.5f * lvr +
             0.5f * __expf(-lvt) * topo + 0.5f * lvt;
    out[1] = recon;
    out[2] = topo;
}

extern "C" void kernel_launch(void* const* d_in, const int* in_sizes, int n_in,
                              void* d_out, int out_size, void* d_ws, size_t ws_size,
                              hipStream_t stream) {
    const float* xo = (const float*)d_in[0];
    const float* xr = (const float*)d_in[1];
    const float* z  = (const float*)d_in[2];
    const float* lsl = (const float*)d_in[3];
    const float* lvr = (const float*)d_in[4];
    const float* lvt = (const float*)d_in[5];
    float* out = (float*)d_out;
    float* ws = (float*)d_ws;

    // ws layout (floats)
    float* acc = ws;                    // [0..2] ot sums, [3] recon sum, [4] sigma_orig
    float* xn  = ws + 64;               // 256*4096
    float* zn  = xn + 1048576;          // 256*256
    float* Do  = zn + 65536;
    float* Dl  = Do + 65536;
    float* Po  = Dl + 65536;
    float* Pl  = Po + 65536;
    float* ELo = Pl + 65536;
    float* ELl = ELo + 65536;
    float* Kh  = ELl + 65536;           // 65536 f16 = 32768 floats
    float* part = Kh + 32768;           // 16*65536

    k_init<<<1, 64, 0, stream>>>(acc);
    k_recon<<<256, 256, 0, stream>>>(xo, xr, acc + 3);
    k_normalize<<<256, 256, 0, stream>>>(xo, xn, 4096);
    k_normalize<<<256, 256, 0, stream>>>(z, zn, 256);
    k_gemm_aat<<<dim3(4, 4, 16), 256, 0, stream>>>(xn, 4096, part);
    k_reduce_d<<<256, 256, 0, stream>>>(part, 16, Do);
    k_gemm_aat<<<dim3(4, 4, 1), 256, 0, stream>>>(zn, 256, part);
    k_reduce_d<<<256, 256, 0, stream>>>(part, 1, Dl);
    k_median<<<1, 1024, 0, stream>>>(Do, acc + 4);
    k_prep<<<256, 256, 0, stream>>>(Do, Dl, acc, lsl, Po, Pl, ELo, ELl, (f16*)Kh);
    k_sinkhorn<<<256, 512, 0, stream>>>(Po, Pl, ELo, ELl, (const uint4*)Kh, acc);
    k_final<<<1, 1, 0, stream>>>(acc, lvr, lvt, out);
}

// Round 2
// 293.133 us; speedup vs baseline: 1.2909x; 1.2909x over previous
//
#include <hip/hip_runtime.h>
#include <hip/hip_fp16.h>

#define EPS 0.1f
#define SINK_ITERS 50
#define KSCALE_LN 9.0109133472f   /* 13*ln2 : K scaled by 2^13 into f16 normal range */

typedef _Float16 f16;
typedef _Float16 f16x2 __attribute__((ext_vector_type(2)));

#ifndef __has_builtin
#define __has_builtin(x) 0
#endif
#if __has_builtin(__builtin_amdgcn_fdot2)
#define HAVE_FDOT2 1
#else
#define HAVE_FDOT2 0
#endif

__device__ __forceinline__ float wave_red_sum(float v) {
    #pragma unroll
    for (int o = 32; o; o >>= 1) v += __shfl_xor(v, o, 64);
    return v;
}

__device__ __forceinline__ float dp2(unsigned kp, unsigned up, float acc) {
#if HAVE_FDOT2
    return __builtin_amdgcn_fdot2(__builtin_bit_cast(f16x2, kp),
                                  __builtin_bit_cast(f16x2, up), acc, false);
#else
    f16x2 k2 = __builtin_bit_cast(f16x2, kp);
    f16x2 u2 = __builtin_bit_cast(f16x2, up);
    acc = fmaf((float)k2.x, (float)u2.x, acc);
    acc = fmaf((float)k2.y, (float)u2.y, acc);
    return acc;
#endif
}

__device__ __forceinline__ float dp8(uint4 kv, uint4 uv, float acc) {
    acc = dp2(kv.x, uv.x, acc);
    acc = dp2(kv.y, uv.y, acc);
    acc = dp2(kv.z, uv.z, acc);
    acc = dp2(kv.w, uv.w, acc);
    return acc;
}

// ---------------- init: zero ws accumulators ----------------
__global__ void k_init(float* acc) {
    if (threadIdx.x < 16) acc[threadIdx.x] = 0.f;
}

// ---------------- recon loss: sum (xr-xo)^2 over 256*4096 (float4) ----------------
__global__ __launch_bounds__(256) void k_recon(const float4* __restrict__ xo,
                                               const float4* __restrict__ xr,
                                               float* __restrict__ acc) {
    __shared__ float red[4];
    int tid = blockIdx.x * 256 + threadIdx.x;
    float s = 0.f;
    for (int i = tid; i < 262144; i += gridDim.x * 256) {
        float4 a = xo[i], b = xr[i];
        float d0 = b.x - a.x, d1 = b.y - a.y, d2 = b.z - a.z, d3 = b.w - a.w;
        s = fmaf(d0, d0, s); s = fmaf(d1, d1, s);
        s = fmaf(d2, d2, s); s = fmaf(d3, d3, s);
    }
    s = wave_red_sum(s);
    if ((threadIdx.x & 63) == 0) red[threadIdx.x >> 6] = s;
    __syncthreads();
    if (threadIdx.x == 0) atomicAdd(acc, red[0] + red[1] + red[2] + red[3]);
}

// ---------------- row-normalize: xn = x / sqrt(max(sum x^2,1e-8)) (float4) ----------------
__global__ __launch_bounds__(256) void k_normalize(const float4* __restrict__ x,
                                                   float4* __restrict__ xn, int c4) {
    __shared__ float red[4];
    int row = blockIdx.x;
    float s = 0.f;
    for (int i = threadIdx.x; i < c4; i += 256) {
        float4 v = x[row * c4 + i];
        s = fmaf(v.x, v.x, s); s = fmaf(v.y, v.y, s);
        s = fmaf(v.z, v.z, s); s = fmaf(v.w, v.w, s);
    }
    s = wave_red_sum(s);
    if ((threadIdx.x & 63) == 0) red[threadIdx.x >> 6] = s;
    __syncthreads();
    float tot = red[0] + red[1] + red[2] + red[3];
    float rn = 1.f / sqrtf(fmaxf(tot, 1e-8f));
    for (int i = threadIdx.x; i < c4; i += 256) {
        float4 v = x[row * c4 + i];
        v.x *= rn; v.y *= rn; v.z *= rn; v.w *= rn;
        xn[row * c4 + i] = v;
    }
}

// ---------------- GEMM: partial[slab] = A_tile @ A_tile^T over nk16*16-wide k slab ----------------
// grid (4,4,slabs), block 256. 64x64 tile, 4x4 micro-tile.
__global__ __launch_bounds__(256) void k_gemm_aat(const float* __restrict__ A, int lda,
                                                  int nk16, float* __restrict__ part) {
    __shared__ float At[64][17], Bt[64][17];
    int i0 = blockIdx.x * 64, j0 = blockIdx.y * 64, k0 = blockIdx.z * nk16 * 16;
    int t = threadIdx.x, tx = t & 15, ty = t >> 4;
    float acc[4][4] = {};
    for (int kc = 0; kc < nk16 * 16; kc += 16) {
        __syncthreads();
        #pragma unroll
        for (int m = 0; m < 4; m++) {
            int idx = m * 256 + t;
            int kk = idx & 15, row = idx >> 4;
            At[row][kk] = A[(size_t)(i0 + row) * lda + k0 + kc + kk];
            Bt[row][kk] = A[(size_t)(j0 + row) * lda + k0 + kc + kk];
        }
        __syncthreads();
        #pragma unroll
        for (int kk = 0; kk < 16; kk++) {
            float a[4], b[4];
            #pragma unroll
            for (int m = 0; m < 4; m++) a[m] = At[ty * 4 + m][kk];
            #pragma unroll
            for (int n = 0; n < 4; n++) b[n] = Bt[tx * 4 + n][kk];
            #pragma unroll
            for (int m = 0; m < 4; m++)
                #pragma unroll
                for (int n = 0; n < 4; n++)
                    acc[m][n] = fmaf(a[m], b[n], acc[m][n]);
        }
    }
    #pragma unroll
    for (int m = 0; m < 4; m++) {
        float4 v = make_float4(acc[m][0], acc[m][1], acc[m][2], acc[m][3]);
        *(float4*)&part[(size_t)blockIdx.z * 65536 + (i0 + ty * 4 + m) * 256 + j0 + tx * 4] = v;
    }
}

// ---------------- D = clip(1 - sum_slabs partial, 0) ----------------
__global__ __launch_bounds__(256) void k_reduce_d(const float* __restrict__ part, int nslab,
                                                  float* __restrict__ D) {
    int e = blockIdx.x * 256 + threadIdx.x;
    float s = 0.f;
    for (int sl = 0; sl < nslab; sl++) s += part[(size_t)sl * 65536 + e];
    float v = 1.f - s;
    D[e] = v > 0.f ? v : 0.f;
}

// ---------------- exact median of 65536 non-negative floats ----------------
// 8192-bin LDS histogram (bin width 2^-12 over [0,2]) + block scan to locate the
// two middle ranks' bins, then short uint-bitpattern bisection inside each bin.
__device__ __forceinline__ int med_bin(float v) {
    int b = (int)(v * 4096.f);
    // make binning exactly consistent with boundaries b/4096 (RN of v*4096 can be off by 1)
    if (v < (float)b * (1.f / 4096.f)) b--;
    else if (v >= (float)(b + 1) * (1.f / 4096.f)) b++;
    if (b < 0) b = 0;
    if (b > 8191) b = 8191;
    return b;
}

__global__ __launch_bounds__(1024) void k_median(const float* __restrict__ D,
                                                 float* __restrict__ out_sigma) {
    __shared__ int hist[8192];
    __shared__ int redc[16];
    __shared__ int sh_bin[2];
    __shared__ int sh_tot;
    int t = threadIdx.x;
    unsigned r[64];
    #pragma unroll
    for (int i = 0; i < 64; i++) r[i] = __float_as_uint(D[t + i * 1024]);
    #pragma unroll
    for (int j = 0; j < 8; j++) hist[t + j * 1024] = 0;
    __syncthreads();
    #pragma unroll
    for (int i = 0; i < 64; i++)
        atomicAdd(&hist[med_bin(__uint_as_float(r[i]))], 1);
    __syncthreads();
    // chunk sums (8 bins per thread) + block exclusive scan
    int s8 = 0;
    #pragma unroll
    for (int j = 0; j < 8; j++) s8 += hist[t * 8 + j];
    int inc = s8;
    #pragma unroll
    for (int o = 1; o < 64; o <<= 1) {
        int vv = __shfl_up(inc, o, 64);
        if ((t & 63) >= o) inc += vv;
    }
    if ((t & 63) == 63) redc[t >> 6] = inc;
    __syncthreads();
    int woff = 0;
    for (int wv = 0; wv < (t >> 6); wv++) woff += redc[wv];
    int excl = woff + inc - s8;
    // locate bin for each target rank
    for (int sel = 0; sel < 2; sel++) {
        int k = 32767 + sel;
        if (excl <= k && k < excl + s8) {
            int cum = excl, bfound = 8191;
            bool found = false;
            for (int j = 0; j < 8; j++) {
                int hc = hist[t * 8 + j];
                if (!found) {
                    if (cum + hc > k) { bfound = t * 8 + j; found = true; }
                    else cum += hc;
                }
            }
            sh_bin[sel] = bfound;
        }
    }
    __syncthreads();
    unsigned res[2];
    for (int sel = 0; sel < 2; sel++) {
        int k = 32767 + sel;
        int b = sh_bin[sel];
        unsigned lo = __float_as_uint((float)b * (1.f / 4096.f));
        unsigned hi = __float_as_uint((float)(b + 1) * (1.f / 4096.f));
        // invariant: count_less(lo) <= k < count_less(hi)
        while (hi - lo > 1u) {
            unsigned mid = (lo + hi) >> 1;
            int c = 0;
            #pragma unroll
            for (int i = 0; i < 64; i++) c += (r[i] < mid) ? 1 : 0;
            #pragma unroll
            for (int o = 32; o; o >>= 1) c += __shfl_xor(c, o, 64);
            if ((t & 63) == 0) redc[t >> 6] = c;
            __syncthreads();
            if (t == 0) {
                int tot = 0;
                for (int wv = 0; wv < 16; wv++) tot += redc[wv];
                sh_tot = tot;
            }
            __syncthreads();
            if (sh_tot <= k) lo = mid; else hi = mid;
        }
        res[sel] = lo;
    }
    if (t == 0)
        out_sigma[0] = 0.5f * (__uint_as_float(res[0]) + __uint_as_float(res[1]));
}

// ---------------- prep: S, P, EPS*logP, and scaled f16 kernel K ----------------
__global__ __launch_bounds__(256) void k_prep(const float* __restrict__ Do,
                                              const float* __restrict__ Dl,
                                              const float* __restrict__ wsacc,
                                              const float* __restrict__ lsl,
                                              float* __restrict__ Po, float* __restrict__ Pl,
                                              float* __restrict__ ELo, float* __restrict__ ELl,
                                              f16* __restrict__ Kh) {
    __shared__ float red[8];
    int i = blockIdx.x, j = threadIdx.x;
    float sig_o = wsacc[4];
    if (sig_o == 0.f) sig_o = 1e-6f;
    float x = lsl[0];
    float sp = (x > 20.f) ? x : log1pf(__expf(x));
    float sig_l = sp + 1e-6f;
    float i2o = 1.f / (2.f * sig_o * sig_o);
    float i2l = 1.f / (2.f * sig_l * sig_l);
    float d_o = Do[i * 256 + j], d_l = Dl[i * 256 + j];
    float so = (i == j) ? 0.f : __expf(-d_o * d_o * i2o);
    float sl = (i == j) ? 0.f : __expf(-d_l * d_l * i2l);
    float wso = wave_red_sum(so);
    float wsl = wave_red_sum(sl);
    if ((j & 63) == 0) { red[j >> 6] = wso; red[4 + (j >> 6)] = wsl; }
    __syncthreads();
    float sum_o = red[0] + red[1] + red[2] + red[3];
    float sum_l = red[4] + red[5] + red[6] + red[7];
    float po = so / fmaxf(sum_o, 1e-8f);
    float pl = sl / fmaxf(sum_l, 1e-8f);
    Po[i * 256 + j] = po;
    Pl[i * 256 + j] = pl;
    ELo[i * 256 + j] = EPS * __logf(fmaxf(po, 1e-8f));
    ELl[i * 256 + j] = EPS * __logf(fmaxf(pl, 1e-8f));
    // K'[k=i][c=j] = exp(-C/eps) * 2^13, packed so column c's k-octet is b128-readable:
    // half index = ((k>>3)*256 + c)*8 + (k&7)
    float kv = __expf(-d_o * (1.f / EPS) + KSCALE_LN);
    Kh[(((i >> 3) * 256 + j) << 3) + (i & 7)] = (f16)kv;
}

// ---------------- Sinkhorn: grid 256 x 1024, 3 problems per wg, K in registers ----------------
// thread t: c2 = t&127 owns columns {c2, c2+128}; h = t>>7 owns k in [h*32, h*32+32).
// K fragment = 8 uint4 = 32 VGPRs (kept resident). 2 barriers per half-step.
__global__ __launch_bounds__(1024, 4) void k_sinkhorn(const float* __restrict__ Po,
                                                      const float* __restrict__ Pl,
                                                      const float* __restrict__ ELo,
                                                      const float* __restrict__ ELl,
                                                      const uint4* __restrict__ Kq,
                                                      float* __restrict__ wsacc) {
    __shared__ float F[3][256], G[3][256], ELa[3][256], ELb[3][256];
    __shared__ __align__(16) f16 UH[3][256];
    __shared__ float ZP[3][8][256];
    __shared__ float red[16];
    int t = threadIdx.x, c2 = t & 127, h = t >> 7;
    int w = blockIdx.x;

    // K fragment: 2 columns x 4 k-octets
    uint4 ka[4], kb[4];
    #pragma unroll
    for (int s = 0; s < 4; s++) {
        ka[s] = Kq[(h * 4 + s) * 256 + c2];
        kb[s] = Kq[(h * 4 + s) * 256 + c2 + 128];
    }

    if (t < 768) {
        int q = t >> 8, c = t & 255;
        int r = w * 3 + q, s = r >> 8, i = r & 255;
        ELa[q][c] = ((s == 1 ? ELl : ELo) + i * 256)[c];
        ELb[q][c] = ((s == 2 ? ELo : ELl) + i * 256)[c];
        UH[q][c] = (f16)1.0f;   // exp(f=0)
    }

    const uint4* upp = (const uint4*)&UH[0][0];  // q-stride = 32 uint4
    for (int it = 0; it < 2 * SINK_ITERS; it++) {
        __syncthreads();   // UH (and init) visible; previous ZP reads complete
        float a0 = 0.f, a1 = 0.f, a2 = 0.f, b0 = 0.f, b1 = 0.f, b2 = 0.f;
        #pragma unroll
        for (int s = 0; s < 4; s++) {
            int ui = h * 4 + s;
            uint4 u0 = upp[ui];
            uint4 u1 = upp[32 + ui];
            uint4 u2 = upp[64 + ui];
            a0 = dp8(ka[s], u0, a0); b0 = dp8(kb[s], u0, b0);
            a1 = dp8(ka[s], u1, a1); b1 = dp8(kb[s], u1, b1);
            a2 = dp8(ka[s], u2, a2); b2 = dp8(kb[s], u2, b2);
        }
        ZP[0][h][c2] = a0; ZP[0][h][c2 + 128] = b0;
        ZP[1][h][c2] = a1; ZP[1][h][c2 + 128] = b1;
        ZP[2][h][c2] = a2; ZP[2][h][c2 + 128] = b2;
        __syncthreads();   // ZP ready
        if (t < 768) {
            int q = t >> 8, c = t & 255;
            float z = 0.f;
            #pragma unroll
            for (int j = 0; j < 8; j++) z += ZP[q][j][c];
            float d = ((it & 1) ? ELa : ELb)[q][c] - EPS * (__logf(z) - KSCALE_LN);
            ((it & 1) ? F : G)[q][c] = d;
            UH[q][c] = (f16)__expf(d);   // u for next half-step
        }
    }
    __syncthreads();

    // cost = sum_k a[k] f[k] + b[k] g[k] per problem; q is wave-uniform for t<768
    float cost = 0.f;
    if (t < 768) {
        int q = t >> 8, c = t & 255;
        int r = w * 3 + q, s = r >> 8, i = r & 255;
        const float* Pa = (s == 1 ? Pl : Po) + i * 256;
        const float* Pb = (s == 2 ? Po : Pl) + i * 256;
        cost = Pa[c] * F[q][c] + Pb[c] * G[q][c];
    }
    float v = wave_red_sum(cost);
    if ((t & 63) == 0) red[t >> 6] = v;
    __syncthreads();
    if (t < 3) {
        float s = red[t * 4] + red[t * 4 + 1] + red[t * 4 + 2] + red[t * 4 + 3];
        int r = w * 3 + t;
        atomicAdd(&wsacc[r >> 8], s);
    }
}

// ---------------- finalize ----------------
__global__ void k_final(const float* __restrict__ wsacc, const float* __restrict__ lvr_p,
                        const float* __restrict__ lvt_p, float* __restrict__ out) {
    float recon = wsacc[3] * (1.f / (256.f * 4096.f));
    float ot0 = wsacc[0] * (1.f / 256.f);
    float ot1 = wsacc[1] * (1.f / 256.f);
    float ot2 = wsacc[2] * (1.f / 256.f);
    float topo = ot0 - 0.5f * ot1 - 0.5f * ot2;
    topo = topo > 0.f ? topo : 0.f;  // * TOPO_MULT (=1)
    float lvr = lvr_p[0], lvt = lvt_p[0];
    out[0] = 0.5f * __expf(-lvr) * recon + 0.5f * lvr +
             0.5f * __expf(-lvt) * topo + 0.5f * lvt;
    out[1] = recon;
    out[2] = topo;
}

extern "C" void kernel_launch(void* const* d_in, const int* in_sizes, int n_in,
                              void* d_out, int out_size, void* d_ws, size_t ws_size,
                              hipStream_t stream) {
    const float* xo = (const float*)d_in[0];
    const float* xr = (const float*)d_in[1];
    const float* z  = (const float*)d_in[2];
    const float* lsl = (const float*)d_in[3];
    const float* lvr = (const float*)d_in[4];
    const float* lvt = (const float*)d_in[5];
    float* out = (float*)d_out;
    float* ws = (float*)d_ws;

    // ws layout (floats)
    float* acc = ws;                    // [0..2] ot sums, [3] recon sum, [4] sigma_orig
    float* xn  = ws + 64;               // 256*4096
    float* zn  = xn + 1048576;          // 256*256
    float* Do  = zn + 65536;
    float* Dl  = Do + 65536;
    float* Po  = Dl + 65536;
    float* Pl  = Po + 65536;
    float* ELo = Pl + 65536;
    float* ELl = ELo + 65536;
    float* Kh  = ELl + 65536;           // 65536 f16 = 32768 floats
    float* part = Kh + 32768;           // 16*65536

    k_init<<<1, 64, 0, stream>>>(acc);
    k_recon<<<512, 256, 0, stream>>>((const float4*)xo, (const float4*)xr, acc + 3);
    k_normalize<<<256, 256, 0, stream>>>((const float4*)xo, (float4*)xn, 1024);
    k_normalize<<<256, 256, 0, stream>>>((const float4*)z, (float4*)zn, 64);
    k_gemm_aat<<<dim3(4, 4, 16), 256, 0, stream>>>(xn, 4096, 16, part);
    k_reduce_d<<<256, 256, 0, stream>>>(part, 16, Do);
    k_gemm_aat<<<dim3(4, 4, 4), 256, 0, stream>>>(zn, 256, 4, part);
    k_reduce_d<<<256, 256, 0, stream>>>(part, 4, Dl);
    k_median<<<1, 1024, 0, stream>>>(Do, acc + 4);
    k_prep<<<256, 256, 0, stream>>>(Do, Dl, acc, lsl, Po, Pl, ELo, ELl, (f16*)Kh);
    k_sinkhorn<<<256, 1024, 0, stream>>>(Po, Pl, ELo, ELl, (const uint4*)Kh, acc);
    k_final<<<1, 1, 0, stream>>>(acc, lvr, lvt, out);
}

// Round 3
// 291.773 us; speedup vs baseline: 1.2970x; 1.0047x over previous
//
#include <hip/hip_runtime.h>
#include <hip/hip_fp16.h>

#define EPS 0.1f
#define SINK_ITERS 50
#define KSCALE_LN 9.0109133472f   /* 13*ln2 : K scaled by 2^13 into f16 normal range */

typedef _Float16 f16;
typedef _Float16 f16x2 __attribute__((ext_vector_type(2)));

#ifndef __has_builtin
#define __has_builtin(x) 0
#endif
#if __has_builtin(__builtin_amdgcn_fdot2)
#define HAVE_FDOT2 1
#else
#define HAVE_FDOT2 0
#endif

__device__ __forceinline__ float wave_red_sum(float v) {
    #pragma unroll
    for (int o = 32; o; o >>= 1) v += __shfl_xor(v, o, 64);
    return v;
}

__device__ __forceinline__ float dp2(unsigned kp, unsigned up, float acc) {
#if HAVE_FDOT2
    return __builtin_amdgcn_fdot2(__builtin_bit_cast(f16x2, kp),
                                  __builtin_bit_cast(f16x2, up), acc, false);
#else
    f16x2 k2 = __builtin_bit_cast(f16x2, kp);
    f16x2 u2 = __builtin_bit_cast(f16x2, up);
    acc = fmaf((float)k2.x, (float)u2.x, acc);
    acc = fmaf((float)k2.y, (float)u2.y, acc);
    return acc;
#endif
}

__device__ __forceinline__ float dp8(uint4 kv, uint4 uv, float acc) {
    acc = dp2(kv.x, uv.x, acc);
    acc = dp2(kv.y, uv.y, acc);
    acc = dp2(kv.z, uv.z, acc);
    acc = dp2(kv.w, uv.w, acc);
    return acc;
}

// Force a uint4's components to live in VGPRs (defeats load rematerialization).
#define PIN_U4(v) asm volatile("" : "+v"(v.x), "+v"(v.y), "+v"(v.z), "+v"(v.w))

// ---------------- init: zero ws accumulators ----------------
__global__ void k_init(float* acc) {
    if (threadIdx.x < 16) acc[threadIdx.x] = 0.f;
}

// ---------------- recon loss: sum (xr-xo)^2 over 256*4096 (float4) ----------------
__global__ __launch_bounds__(256) void k_recon(const float4* __restrict__ xo,
                                               const float4* __restrict__ xr,
                                               float* __restrict__ acc) {
    __shared__ float red[4];
    int tid = blockIdx.x * 256 + threadIdx.x;
    float s = 0.f;
    for (int i = tid; i < 262144; i += gridDim.x * 256) {
        float4 a = xo[i], b = xr[i];
        float d0 = b.x - a.x, d1 = b.y - a.y, d2 = b.z - a.z, d3 = b.w - a.w;
        s = fmaf(d0, d0, s); s = fmaf(d1, d1, s);
        s = fmaf(d2, d2, s); s = fmaf(d3, d3, s);
    }
    s = wave_red_sum(s);
    if ((threadIdx.x & 63) == 0) red[threadIdx.x >> 6] = s;
    __syncthreads();
    if (threadIdx.x == 0) atomicAdd(acc, red[0] + red[1] + red[2] + red[3]);
}

// ---------------- row-normalize: xn = x / sqrt(max(sum x^2,1e-8)) (float4) ----------------
__global__ __launch_bounds__(256) void k_normalize(const float4* __restrict__ x,
                                                   float4* __restrict__ xn, int c4) {
    __shared__ float red[4];
    int row = blockIdx.x;
    float s = 0.f;
    for (int i = threadIdx.x; i < c4; i += 256) {
        float4 v = x[row * c4 + i];
        s = fmaf(v.x, v.x, s); s = fmaf(v.y, v.y, s);
        s = fmaf(v.z, v.z, s); s = fmaf(v.w, v.w, s);
    }
    s = wave_red_sum(s);
    if ((threadIdx.x & 63) == 0) red[threadIdx.x >> 6] = s;
    __syncthreads();
    float tot = red[0] + red[1] + red[2] + red[3];
    float rn = 1.f / sqrtf(fmaxf(tot, 1e-8f));
    for (int i = threadIdx.x; i < c4; i += 256) {
        float4 v = x[row * c4 + i];
        v.x *= rn; v.y *= rn; v.z *= rn; v.w *= rn;
        xn[row * c4 + i] = v;
    }
}

// ---------------- GEMM: partial[slab] = A_tile @ A_tile^T over nk16*16-wide k slab ----------------
// grid (4,4,slabs), block 256. 64x64 tile, 4x4 micro-tile.
__global__ __launch_bounds__(256) void k_gemm_aat(const float* __restrict__ A, int lda,
                                                  int nk16, float* __restrict__ part) {
    __shared__ float At[64][17], Bt[64][17];
    int i0 = blockIdx.x * 64, j0 = blockIdx.y * 64, k0 = blockIdx.z * nk16 * 16;
    int t = threadIdx.x, tx = t & 15, ty = t >> 4;
    float acc[4][4] = {};
    for (int kc = 0; kc < nk16 * 16; kc += 16) {
        __syncthreads();
        #pragma unroll
        for (int m = 0; m < 4; m++) {
            int idx = m * 256 + t;
            int kk = idx & 15, row = idx >> 4;
            At[row][kk] = A[(size_t)(i0 + row) * lda + k0 + kc + kk];
            Bt[row][kk] = A[(size_t)(j0 + row) * lda + k0 + kc + kk];
        }
        __syncthreads();
        #pragma unroll
        for (int kk = 0; kk < 16; kk++) {
            float a[4], b[4];
            #pragma unroll
            for (int m = 0; m < 4; m++) a[m] = At[ty * 4 + m][kk];
            #pragma unroll
            for (int n = 0; n < 4; n++) b[n] = Bt[tx * 4 + n][kk];
            #pragma unroll
            for (int m = 0; m < 4; m++)
                #pragma unroll
                for (int n = 0; n < 4; n++)
                    acc[m][n] = fmaf(a[m], b[n], acc[m][n]);
        }
    }
    #pragma unroll
    for (int m = 0; m < 4; m++) {
        float4 v = make_float4(acc[m][0], acc[m][1], acc[m][2], acc[m][3]);
        *(float4*)&part[(size_t)blockIdx.z * 65536 + (i0 + ty * 4 + m) * 256 + j0 + tx * 4] = v;
    }
}

// ---------------- D = clip(1 - sum_slabs partial, 0) ----------------
__global__ __launch_bounds__(256) void k_reduce_d(const float* __restrict__ part, int nslab,
                                                  float* __restrict__ D) {
    int e = blockIdx.x * 256 + threadIdx.x;
    float s = 0.f;
    for (int sl = 0; sl < nslab; sl++) s += part[(size_t)sl * 65536 + e];
    float v = 1.f - s;
    D[e] = v > 0.f ? v : 0.f;
}

// ---------------- exact median of 65536 non-negative floats ----------------
// 8192-bin LDS histogram (bin width 2^-12 over [0,2]) + block scan to locate the
// two middle ranks' bins, then short uint-bitpattern bisection inside each bin.
__device__ __forceinline__ int med_bin(float v) {
    int b = (int)(v * 4096.f);
    if (v < (float)b * (1.f / 4096.f)) b--;
    else if (v >= (float)(b + 1) * (1.f / 4096.f)) b++;
    if (b < 0) b = 0;
    if (b > 8191) b = 8191;
    return b;
}

__global__ __launch_bounds__(1024) void k_median(const float* __restrict__ D,
                                                 float* __restrict__ out_sigma) {
    __shared__ int hist[8192];
    __shared__ int redc[16];
    __shared__ int sh_bin[2];
    __shared__ int sh_tot;
    int t = threadIdx.x;
    unsigned r[64];
    #pragma unroll
    for (int i = 0; i < 64; i++) r[i] = __float_as_uint(D[t + i * 1024]);
    #pragma unroll
    for (int j = 0; j < 8; j++) hist[t + j * 1024] = 0;
    __syncthreads();
    #pragma unroll
    for (int i = 0; i < 64; i++)
        atomicAdd(&hist[med_bin(__uint_as_float(r[i]))], 1);
    __syncthreads();
    int s8 = 0;
    #pragma unroll
    for (int j = 0; j < 8; j++) s8 += hist[t * 8 + j];
    int inc = s8;
    #pragma unroll
    for (int o = 1; o < 64; o <<= 1) {
        int vv = __shfl_up(inc, o, 64);
        if ((t & 63) >= o) inc += vv;
    }
    if ((t & 63) == 63) redc[t >> 6] = inc;
    __syncthreads();
    int woff = 0;
    for (int wv = 0; wv < (t >> 6); wv++) woff += redc[wv];
    int excl = woff + inc - s8;
    for (int sel = 0; sel < 2; sel++) {
        int k = 32767 + sel;
        if (excl <= k && k < excl + s8) {
            int cum = excl, bfound = 8191;
            bool found = false;
            for (int j = 0; j < 8; j++) {
                int hc = hist[t * 8 + j];
                if (!found) {
                    if (cum + hc > k) { bfound = t * 8 + j; found = true; }
                    else cum += hc;
                }
            }
            sh_bin[sel] = bfound;
        }
    }
    __syncthreads();
    unsigned res[2];
    for (int sel = 0; sel < 2; sel++) {
        int k = 32767 + sel;
        int b = sh_bin[sel];
        unsigned lo = __float_as_uint((float)b * (1.f / 4096.f));
        unsigned hi = __float_as_uint((float)(b + 1) * (1.f / 4096.f));
        while (hi - lo > 1u) {
            unsigned mid = (lo + hi) >> 1;
            int c = 0;
            #pragma unroll
            for (int i = 0; i < 64; i++) c += (r[i] < mid) ? 1 : 0;
            #pragma unroll
            for (int o = 32; o; o >>= 1) c += __shfl_xor(c, o, 64);
            if ((t & 63) == 0) redc[t >> 6] = c;
            __syncthreads();
            if (t == 0) {
                int tot = 0;
                for (int wv = 0; wv < 16; wv++) tot += redc[wv];
                sh_tot = tot;
            }
            __syncthreads();
            if (sh_tot <= k) lo = mid; else hi = mid;
        }
        res[sel] = lo;
    }
    if (t == 0)
        out_sigma[0] = 0.5f * (__uint_as_float(res[0]) + __uint_as_float(res[1]));
}

// ---------------- prep: S, P, EPS*logP, and scaled f16 kernel K ----------------
__global__ __launch_bounds__(256) void k_prep(const float* __restrict__ Do,
                                              const float* __restrict__ Dl,
                                              const float* __restrict__ wsacc,
                                              const float* __restrict__ lsl,
                                              float* __restrict__ Po, float* __restrict__ Pl,
                                              float* __restrict__ ELo, float* __restrict__ ELl,
                                              f16* __restrict__ Kh) {
    __shared__ float red[8];
    int i = blockIdx.x, j = threadIdx.x;
    float sig_o = wsacc[4];
    if (sig_o == 0.f) sig_o = 1e-6f;
    float x = lsl[0];
    float sp = (x > 20.f) ? x : log1pf(__expf(x));
    float sig_l = sp + 1e-6f;
    float i2o = 1.f / (2.f * sig_o * sig_o);
    float i2l = 1.f / (2.f * sig_l * sig_l);
    float d_o = Do[i * 256 + j], d_l = Dl[i * 256 + j];
    float so = (i == j) ? 0.f : __expf(-d_o * d_o * i2o);
    float sl = (i == j) ? 0.f : __expf(-d_l * d_l * i2l);
    float wso = wave_red_sum(so);
    float wsl = wave_red_sum(sl);
    if ((j & 63) == 0) { red[j >> 6] = wso; red[4 + (j >> 6)] = wsl; }
    __syncthreads();
    float sum_o = red[0] + red[1] + red[2] + red[3];
    float sum_l = red[4] + red[5] + red[6] + red[7];
    float po = so / fmaxf(sum_o, 1e-8f);
    float pl = sl / fmaxf(sum_l, 1e-8f);
    Po[i * 256 + j] = po;
    Pl[i * 256 + j] = pl;
    ELo[i * 256 + j] = EPS * __logf(fmaxf(po, 1e-8f));
    ELl[i * 256 + j] = EPS * __logf(fmaxf(pl, 1e-8f));
    // K'[k=i][c=j] = exp(-C/eps) * 2^13, packed so column c's k-octet is b128-readable:
    // half index = ((k>>3)*256 + c)*8 + (k&7)
    float kv = __expf(-d_o * (1.f / EPS) + KSCALE_LN);
    Kh[(((i >> 3) * 256 + j) << 3) + (i & 7)] = (f16)kv;
}

// ---------------- Sinkhorn: grid 256 x 1024, 3 problems per wg, K pinned in registers ----------------
// thread t: c2 = t&127 owns columns {c2, c2+128}; h = t>>7 owns k in [h*32, h*32+32).
// K fragment = 8 uint4 = 32 VGPRs, pinned via asm so the compiler cannot
// rematerialize the loads inside the 100-step loop (it did at 32 VGPRs -> 24 TB/s
// of L2 re-reads). 2 barriers per half-step.
__global__ __launch_bounds__(1024, 4) void k_sinkhorn(const float* __restrict__ Po,
                                                      const float* __restrict__ Pl,
                                                      const float* __restrict__ ELo,
                                                      const float* __restrict__ ELl,
                                                      const uint4* __restrict__ Kq,
                                                      float* __restrict__ wsacc) {
    __shared__ float F[3][256], G[3][256], ELa[3][256], ELb[3][256];
    __shared__ __align__(16) f16 UH[3][256];
    __shared__ float ZP[3][8][256];
    __shared__ float red[16];
    int t = threadIdx.x, c2 = t & 127, h = t >> 7;
    int w = blockIdx.x;

    // K fragment: 2 columns x 4 k-octets
    uint4 ka[4], kb[4];
    #pragma unroll
    for (int s = 0; s < 4; s++) {
        ka[s] = Kq[(h * 4 + s) * 256 + c2];
        kb[s] = Kq[(h * 4 + s) * 256 + c2 + 128];
    }
    #pragma unroll
    for (int s = 0; s < 4; s++) { PIN_U4(ka[s]); PIN_U4(kb[s]); }

    if (t < 768) {
        int q = t >> 8, c = t & 255;
        int r = w * 3 + q, s = r >> 8, i = r & 255;
        ELa[q][c] = ((s == 1 ? ELl : ELo) + i * 256)[c];
        ELb[q][c] = ((s == 2 ? ELo : ELl) + i * 256)[c];
        UH[q][c] = (f16)1.0f;   // exp(f=0)
    }

    const uint4* upp = (const uint4*)&UH[0][0];  // q-stride = 32 uint4
    for (int it = 0; it < 2 * SINK_ITERS; it++) {
        __syncthreads();   // UH (and init) visible; previous ZP reads complete
        float a0 = 0.f, a1 = 0.f, a2 = 0.f, b0 = 0.f, b1 = 0.f, b2 = 0.f;
        #pragma unroll
        for (int s = 0; s < 4; s++) {
            int ui = h * 4 + s;
            uint4 u0 = upp[ui];
            uint4 u1 = upp[32 + ui];
            uint4 u2 = upp[64 + ui];
            a0 = dp8(ka[s], u0, a0); b0 = dp8(kb[s], u0, b0);
            a1 = dp8(ka[s], u1, a1); b1 = dp8(kb[s], u1, b1);
            a2 = dp8(ka[s], u2, a2); b2 = dp8(kb[s], u2, b2);
        }
        ZP[0][h][c2] = a0; ZP[0][h][c2 + 128] = b0;
        ZP[1][h][c2] = a1; ZP[1][h][c2 + 128] = b1;
        ZP[2][h][c2] = a2; ZP[2][h][c2 + 128] = b2;
        __syncthreads();   // ZP ready
        if (t < 768) {
            int q = t >> 8, c = t & 255;
            float z = 0.f;
            #pragma unroll
            for (int j = 0; j < 8; j++) z += ZP[q][j][c];
            float d = ((it & 1) ? ELa : ELb)[q][c] - EPS * (__logf(z) - KSCALE_LN);
            ((it & 1) ? F : G)[q][c] = d;
            UH[q][c] = (f16)__expf(d);   // u for next half-step
        }
    }
    __syncthreads();

    // cost = sum_k a[k] f[k] + b[k] g[k] per problem; q is wave-uniform for t<768
    float cost = 0.f;
    if (t < 768) {
        int q = t >> 8, c = t & 255;
        int r = w * 3 + q, s = r >> 8, i = r & 255;
        const float* Pa = (s == 1 ? Pl : Po) + i * 256;
        const float* Pb = (s == 2 ? Po : Pl) + i * 256;
        cost = Pa[c] * F[q][c] + Pb[c] * G[q][c];
    }
    float v = wave_red_sum(cost);
    if ((t & 63) == 0) red[t >> 6] = v;
    __syncthreads();
    if (t < 3) {
        float s = red[t * 4] + red[t * 4 + 1] + red[t * 4 + 2] + red[t * 4 + 3];
        int r = w * 3 + t;
        atomicAdd(&wsacc[r >> 8], s);
    }
}

// ---------------- finalize ----------------
__global__ void k_final(const float* __restrict__ wsacc, const float* __restrict__ lvr_p,
                        const float* __restrict__ lvt_p, float* __restrict__ out) {
    float recon = wsacc[3] * (1.f / (256.f * 4096.f));
    float ot0 = wsacc[0] * (1.f / 256.f);
    float ot1 = wsacc[1] * (1.f / 256.f);
    float ot2 = wsacc[2] * (1.f / 256.f);
    float topo = ot0 - 0.5f * ot1 - 0.5f * ot2;
    topo = topo > 0.f ? topo : 0.f;  // * TOPO_MULT (=1)
    float lvr = lvr_p[0], lvt = lvt_p[0];
    out[0] = 0.5f * __expf(-lvr) * recon + 0.5f * lvr +
             0.5f * __expf(-lvt) * topo + 0.5f * lvt;
    out[1] = recon;
    out[2] = topo;
}

extern "C" void kernel_launch(void* const* d_in, const int* in_sizes, int n_in,
                              void* d_out, int out_size, void* d_ws, size_t ws_size,
                              hipStream_t stream) {
    const float* xo = (const float*)d_in[0];
    const float* xr = (const float*)d_in[1];
    const float* z  = (const float*)d_in[2];
    const float* lsl = (const float*)d_in[3];
    const float* lvr = (const float*)d_in[4];
    const float* lvt = (const float*)d_in[5];
    float* out = (float*)d_out;
    float* ws = (float*)d_ws;

    // ws layout (floats)
    float* acc = ws;                    // [0..2] ot sums, [3] recon sum, [4] sigma_orig
    float* xn  = ws + 64;               // 256*4096
    float* zn  = xn + 1048576;          // 256*256
    float* Do  = zn + 65536;
    float* Dl  = Do + 65536;
    float* Po  = Dl + 65536;
    float* Pl  = Po + 65536;
    float* ELo = Pl + 65536;
    float* ELl = ELo + 65536;
    float* Kh  = ELl + 65536;           // 65536 f16 = 32768 floats
    float* part = Kh + 32768;           // 16*65536

    k_init<<<1, 64, 0, stream>>>(acc);
    k_recon<<<512, 256, 0, stream>>>((const float4*)xo, (const float4*)xr, acc + 3);
    k_normalize<<<256, 256, 0, stream>>>((const float4*)xo, (float4*)xn, 1024);
    k_normalize<<<256, 256, 0, stream>>>((const float4*)z, (float4*)zn, 64);
    k_gemm_aat<<<dim3(4, 4, 16), 256, 0, stream>>>(xn, 4096, 16, part);
    k_reduce_d<<<256, 256, 0, stream>>>(part, 16, Do);
    k_gemm_aat<<<dim3(4, 4, 4), 256, 0, stream>>>(zn, 256, 4, part);
    k_reduce_d<<<256, 256, 0, stream>>>(part, 4, Dl);
    k_median<<<1, 1024, 0, stream>>>(Do, acc + 4);
    k_prep<<<256, 256, 0, stream>>>(Do, Dl, acc, lsl, Po, Pl, ELo, ELl, (f16*)Kh);
    k_sinkhorn<<<256, 1024, 0, stream>>>(Po, Pl, ELo, ELl, (const uint4*)Kh, acc);
    k_final<<<1, 1, 0, stream>>>(acc, lvr, lvt, out);
}

// Round 4
// 278.070 us; speedup vs baseline: 1.3609x; 1.0493x over previous
//
#include <hip/hip_runtime.h>
#include <hip/hip_fp16.h>

#define EPS 0.1f
#define SINK_ITERS 50
#define KSCALE_LN 9.0109133472f   /* 13*ln2 : K scaled by 2^13 into f16 normal range */

typedef _Float16 f16;
typedef _Float16 f16x2 __attribute__((ext_vector_type(2)));

#ifndef __has_builtin
#define __has_builtin(x) 0
#endif
#if __has_builtin(__builtin_amdgcn_fdot2)
#define HAVE_FDOT2 1
#else
#define HAVE_FDOT2 0
#endif

__device__ __forceinline__ float wave_red_sum(float v) {
    #pragma unroll
    for (int o = 32; o; o >>= 1) v += __shfl_xor(v, o, 64);
    return v;
}

__device__ __forceinline__ float dp2(unsigned kp, unsigned up, float acc) {
#if HAVE_FDOT2
    return __builtin_amdgcn_fdot2(__builtin_bit_cast(f16x2, kp),
                                  __builtin_bit_cast(f16x2, up), acc, false);
#else
    f16x2 k2 = __builtin_bit_cast(f16x2, kp);
    f16x2 u2 = __builtin_bit_cast(f16x2, up);
    acc = fmaf((float)k2.x, (float)u2.x, acc);
    acc = fmaf((float)k2.y, (float)u2.y, acc);
    return acc;
#endif
}

__device__ __forceinline__ float dp8(uint4 kv, uint4 uv, float acc) {
    acc = dp2(kv.x, uv.x, acc);
    acc = dp2(kv.y, uv.y, acc);
    acc = dp2(kv.z, uv.z, acc);
    acc = dp2(kv.w, uv.w, acc);
    return acc;
}

#define PIN_U4(v) asm volatile("" : "+v"(v.x), "+v"(v.y), "+v"(v.z), "+v"(v.w))

// ---------------- recon loss: sum (xr-xo)^2 over 256*4096 (float4) ----------------
__global__ __launch_bounds__(256) void k_recon(const float4* __restrict__ xo,
                                               const float4* __restrict__ xr,
                                               float* __restrict__ acc) {
    __shared__ float red[4];
    int tid = blockIdx.x * 256 + threadIdx.x;
    float s = 0.f;
    for (int i = tid; i < 262144; i += gridDim.x * 256) {
        float4 a = xo[i], b = xr[i];
        float d0 = b.x - a.x, d1 = b.y - a.y, d2 = b.z - a.z, d3 = b.w - a.w;
        s = fmaf(d0, d0, s); s = fmaf(d1, d1, s);
        s = fmaf(d2, d2, s); s = fmaf(d3, d3, s);
    }
    s = wave_red_sum(s);
    if ((threadIdx.x & 63) == 0) red[threadIdx.x >> 6] = s;
    __syncthreads();
    if (threadIdx.x == 0) atomicAdd(acc, red[0] + red[1] + red[2] + red[3]);
}

// ---------------- merged row-normalize for xo (4096 cols) and z (256 cols) ----------------
__global__ __launch_bounds__(256) void k_norm2(const float4* __restrict__ xo,
                                               const float4* __restrict__ z,
                                               float4* __restrict__ xn,
                                               float4* __restrict__ zn) {
    __shared__ float red[4];
    int row = blockIdx.x;
    const float4* src; float4* dst; int c4;
    if (row < 256) { src = xo + (size_t)row * 1024; dst = xn + (size_t)row * 1024; c4 = 1024; }
    else { src = z + (size_t)(row - 256) * 64; dst = zn + (size_t)(row - 256) * 64; c4 = 64; }
    float s = 0.f;
    for (int i = threadIdx.x; i < c4; i += 256) {
        float4 v = src[i];
        s = fmaf(v.x, v.x, s); s = fmaf(v.y, v.y, s);
        s = fmaf(v.z, v.z, s); s = fmaf(v.w, v.w, s);
    }
    s = wave_red_sum(s);
    if ((threadIdx.x & 63) == 0) red[threadIdx.x >> 6] = s;
    __syncthreads();
    float tot = red[0] + red[1] + red[2] + red[3];
    float rn = 1.f / sqrtf(fmaxf(tot, 1e-8f));
    for (int i = threadIdx.x; i < c4; i += 256) {
        float4 v = src[i];
        v.x *= rn; v.y *= rn; v.z *= rn; v.w *= rn;
        dst[i] = v;
    }
}

// ---------------- merged GEMM: A@A^T k-slabs for xn (z<16) and zn (z>=16) ----------------
// grid (4,4,20), block 256. 64x64 tile, 4x4 micro-tile.
__global__ __launch_bounds__(256) void k_gemm_aat(const float* __restrict__ xn,
                                                  const float* __restrict__ zn,
                                                  float* __restrict__ part,
                                                  float* __restrict__ part2) {
    __shared__ float At[64][17], Bt[64][17];
    int zb = blockIdx.z;
    const float* A; int lda, k0, nk; float* out;
    if (zb < 16) { A = xn; lda = 4096; k0 = zb * 256; nk = 256; out = part + (size_t)zb * 65536; }
    else { A = zn; lda = 256; k0 = (zb - 16) * 64; nk = 64; out = part2 + (size_t)(zb - 16) * 65536; }
    int i0 = blockIdx.x * 64, j0 = blockIdx.y * 64;
    int t = threadIdx.x, tx = t & 15, ty = t >> 4;
    float acc[4][4] = {};
    for (int kc = 0; kc < nk; kc += 16) {
        __syncthreads();
        #pragma unroll
        for (int m = 0; m < 4; m++) {
            int idx = m * 256 + t;
            int kk = idx & 15, row = idx >> 4;
            At[row][kk] = A[(size_t)(i0 + row) * lda + k0 + kc + kk];
            Bt[row][kk] = A[(size_t)(j0 + row) * lda + k0 + kc + kk];
        }
        __syncthreads();
        #pragma unroll
        for (int kk = 0; kk < 16; kk++) {
            float a[4], b[4];
            #pragma unroll
            for (int m = 0; m < 4; m++) a[m] = At[ty * 4 + m][kk];
            #pragma unroll
            for (int n = 0; n < 4; n++) b[n] = Bt[tx * 4 + n][kk];
            #pragma unroll
            for (int m = 0; m < 4; m++)
                #pragma unroll
                for (int n = 0; n < 4; n++)
                    acc[m][n] = fmaf(a[m], b[n], acc[m][n]);
        }
    }
    #pragma unroll
    for (int m = 0; m < 4; m++) {
        float4 v = make_float4(acc[m][0], acc[m][1], acc[m][2], acc[m][3]);
        *(float4*)&out[(i0 + ty * 4 + m) * 256 + j0 + tx * 4] = v;
    }
}

// ---------------- merged D = clip(1 - sum partial, 0) for Do (16 slabs) and Dl (4) ----------------
__global__ __launch_bounds__(256) void k_reduce_d(const float* __restrict__ part,
                                                  const float* __restrict__ part2,
                                                  float* __restrict__ Do,
                                                  float* __restrict__ Dl) {
    int b = blockIdx.x;
    if (b < 256) {
        int e = b * 256 + threadIdx.x;
        float s = 0.f;
        for (int sl = 0; sl < 16; sl++) s += part[(size_t)sl * 65536 + e];
        float v = 1.f - s;
        Do[e] = v > 0.f ? v : 0.f;
    } else {
        int e = (b - 256) * 256 + threadIdx.x;
        float s = 0.f;
        for (int sl = 0; sl < 4; sl++) s += part2[(size_t)sl * 65536 + e];
        float v = 1.f - s;
        Dl[e] = v > 0.f ? v : 0.f;
    }
}

// ---------------- exact median of 65536 non-negative floats ----------------
__device__ __forceinline__ int med_bin(float v) {
    int b = (int)(v * 4096.f);
    if (v < (float)b * (1.f / 4096.f)) b--;
    else if (v >= (float)(b + 1) * (1.f / 4096.f)) b++;
    if (b < 0) b = 0;
    if (b > 8191) b = 8191;
    return b;
}

__global__ __launch_bounds__(1024) void k_median(const float* __restrict__ D,
                                                 float* __restrict__ out_sigma) {
    __shared__ int hist[8192];
    __shared__ int redc[16];
    __shared__ int sh_bin[2];
    __shared__ int sh_tot;
    int t = threadIdx.x;
    unsigned r[64];
    #pragma unroll
    for (int i = 0; i < 64; i++) r[i] = __float_as_uint(D[t + i * 1024]);
    #pragma unroll
    for (int j = 0; j < 8; j++) hist[t + j * 1024] = 0;
    __syncthreads();
    #pragma unroll
    for (int i = 0; i < 64; i++)
        atomicAdd(&hist[med_bin(__uint_as_float(r[i]))], 1);
    __syncthreads();
    int s8 = 0;
    #pragma unroll
    for (int j = 0; j < 8; j++) s8 += hist[t * 8 + j];
    int inc = s8;
    #pragma unroll
    for (int o = 1; o < 64; o <<= 1) {
        int vv = __shfl_up(inc, o, 64);
        if ((t & 63) >= o) inc += vv;
    }
    if ((t & 63) == 63) redc[t >> 6] = inc;
    __syncthreads();
    int woff = 0;
    for (int wv = 0; wv < (t >> 6); wv++) woff += redc[wv];
    int excl = woff + inc - s8;
    for (int sel = 0; sel < 2; sel++) {
        int k = 32767 + sel;
        if (excl <= k && k < excl + s8) {
            int cum = excl, bfound = 8191;
            bool found = false;
            for (int j = 0; j < 8; j++) {
                int hc = hist[t * 8 + j];
                if (!found) {
                    if (cum + hc > k) { bfound = t * 8 + j; found = true; }
                    else cum += hc;
                }
            }
            sh_bin[sel] = bfound;
        }
    }
    __syncthreads();
    unsigned res[2];
    for (int sel = 0; sel < 2; sel++) {
        int k = 32767 + sel;
        int b = sh_bin[sel];
        unsigned lo = __float_as_uint((float)b * (1.f / 4096.f));
        unsigned hi = __float_as_uint((float)(b + 1) * (1.f / 4096.f));
        while (hi - lo > 1u) {
            unsigned mid = (lo + hi) >> 1;
            int c = 0;
            #pragma unroll
            for (int i = 0; i < 64; i++) c += (r[i] < mid) ? 1 : 0;
            #pragma unroll
            for (int o = 32; o; o >>= 1) c += __shfl_xor(c, o, 64);
            if ((t & 63) == 0) redc[t >> 6] = c;
            __syncthreads();
            if (t == 0) {
                int tot = 0;
                for (int wv = 0; wv < 16; wv++) tot += redc[wv];
                sh_tot = tot;
            }
            __syncthreads();
            if (sh_tot <= k) lo = mid; else hi = mid;
        }
        res[sel] = lo;
    }
    if (t == 0)
        out_sigma[0] = 0.5f * (__uint_as_float(res[0]) + __uint_as_float(res[1]));
}

// ---------------- prep: S, P, EPS*logP, and scaled f16 kernel K ----------------
__global__ __launch_bounds__(256) void k_prep(const float* __restrict__ Do,
                                              const float* __restrict__ Dl,
                                              const float* __restrict__ wsacc,
                                              const float* __restrict__ lsl,
                                              float* __restrict__ Po, float* __restrict__ Pl,
                                              float* __restrict__ ELo, float* __restrict__ ELl,
                                              f16* __restrict__ Kh) {
    __shared__ float red[8];
    int i = blockIdx.x, j = threadIdx.x;
    float sig_o = wsacc[4];
    if (sig_o == 0.f) sig_o = 1e-6f;
    float x = lsl[0];
    float sp = (x > 20.f) ? x : log1pf(__expf(x));
    float sig_l = sp + 1e-6f;
    float i2o = 1.f / (2.f * sig_o * sig_o);
    float i2l = 1.f / (2.f * sig_l * sig_l);
    float d_o = Do[i * 256 + j], d_l = Dl[i * 256 + j];
    float so = (i == j) ? 0.f : __expf(-d_o * d_o * i2o);
    float sl = (i == j) ? 0.f : __expf(-d_l * d_l * i2l);
    float wso = wave_red_sum(so);
    float wsl = wave_red_sum(sl);
    if ((j & 63) == 0) { red[j >> 6] = wso; red[4 + (j >> 6)] = wsl; }
    __syncthreads();
    float sum_o = red[0] + red[1] + red[2] + red[3];
    float sum_l = red[4] + red[5] + red[6] + red[7];
    float po = so / fmaxf(sum_o, 1e-8f);
    float pl = sl / fmaxf(sum_l, 1e-8f);
    Po[i * 256 + j] = po;
    Pl[i * 256 + j] = pl;
    ELo[i * 256 + j] = EPS * __logf(fmaxf(po, 1e-8f));
    ELl[i * 256 + j] = EPS * __logf(fmaxf(pl, 1e-8f));
    // K'[k=i][c=j] = exp(-C/eps) * 2^13; half index = ((k>>3)*256 + c)*8 + (k&7)
    float kv = __expf(-d_o * (1.f / EPS) + KSCALE_LN);
    Kh[(((i >> 3) * 256 + j) << 3) + (i & 7)] = (f16)kv;
}

// ---------------- Sinkhorn v2.5: grid 256 x 1024, 3 problems/wg ----------------
// Phase-1 thread (c2=t&127, h=t>>7): owns columns {2c2, 2c2+1}, k in [32h,32h+32).
// Phase-2 thread (q2=t>>8, c=t&255) for t<768: owns (problem q2, column c); its
// EL consts, f and g stay in REGISTERS for the whole loop. ZP2 layout [q][c2][18]
// makes phase-1 emit ds_write_b64 (pair of adjacent columns) conflict-free, and
// phase-2 reads stride-2 dwords (bank-spread, pair-mergeable).
__global__ __launch_bounds__(1024, 4) void k_sinkhorn(const float* __restrict__ Po,
                                                      const float* __restrict__ Pl,
                                                      const float* __restrict__ ELo,
                                                      const float* __restrict__ ELl,
                                                      const uint4* __restrict__ Kq,
                                                      float* __restrict__ wsacc) {
    __shared__ __align__(16) float ZP2[3][128][18];   // [q][c2][2h+e], e = col parity
    __shared__ __align__(16) f16 UH[3][256];
    __shared__ float red[16];
    int t = threadIdx.x, c2 = t & 127, h = t >> 7;
    int w = blockIdx.x;

    // K fragments: columns 2c2 / 2c2+1, k-octets h*4+s (register-resident)
    uint4 ka[4], kb[4];
    #pragma unroll
    for (int s = 0; s < 4; s++) {
        ka[s] = Kq[(h * 4 + s) * 256 + 2 * c2];
        kb[s] = Kq[(h * 4 + s) * 256 + 2 * c2 + 1];
    }
    #pragma unroll
    for (int s = 0; s < 4; s++) { PIN_U4(ka[s]); PIN_U4(kb[s]); }

    int q2 = t >> 8, c = t & 255;
    bool p2 = (t < 768);
    float ela = 0.f, elb = 0.f, fv = 0.f, gv = 0.f;
    const float* Pa = Po; const float* Pb = Po;
    if (p2) {
        int r = w * 3 + q2, s = r >> 8, i = r & 255;
        ela = ((s == 1 ? ELl : ELo) + i * 256)[c] + EPS * KSCALE_LN;
        elb = ((s == 2 ? ELo : ELl) + i * 256)[c] + EPS * KSCALE_LN;
        Pa = (s == 1 ? Pl : Po) + i * 256;
        Pb = (s == 2 ? Po : Pl) + i * 256;
        UH[q2][c] = (f16)1.0f;   // exp(f=0)
    }
    const uint4* upp = (const uint4*)&UH[0][0];      // q-stride = 32 uint4 (imm)
    float* zpr = &ZP2[0][c2][2 * h];                 // q-stride = 2304 floats (imm)
    const float* zrd = &ZP2[0][(t & 255) >> 1][t & 1];
    if (p2) zrd = &ZP2[q2][c >> 1][c & 1];
    __syncthreads();

    for (int it = 0; it < 2 * SINK_ITERS; it++) {
        // phase 1: z-partials, K from registers, u uniform-read from LDS
        float a0 = 0.f, a1 = 0.f, a2 = 0.f, b0 = 0.f, b1 = 0.f, b2 = 0.f;
        #pragma unroll
        for (int s = 0; s < 4; s++) {
            int ui = h * 4 + s;
            uint4 u0 = upp[ui], u1 = upp[32 + ui], u2 = upp[64 + ui];
            a0 = dp8(ka[s], u0, a0); b0 = dp8(kb[s], u0, b0);
            a1 = dp8(ka[s], u1, a1); b1 = dp8(kb[s], u1, b1);
            a2 = dp8(ka[s], u2, a2); b2 = dp8(kb[s], u2, b2);
        }
        *(float2*)(zpr)        = make_float2(a0, b0);
        *(float2*)(zpr + 2304) = make_float2(a1, b1);
        *(float2*)(zpr + 4608) = make_float2(a2, b2);
        __syncthreads();
        // phase 2: reduce 8 partials, dual update in registers, u back to LDS
        if (p2) {
            float z = ((zrd[0] + zrd[2]) + (zrd[4] + zrd[6])) +
                      ((zrd[8] + zrd[10]) + (zrd[12] + zrd[14]));
            float el = (it & 1) ? ela : elb;
            float d = el - EPS * __logf(z);
            if (it & 1) fv = d; else gv = d;
            UH[q2][c] = (f16)__expf(d);
        }
        __syncthreads();
    }

    // epilogue: cost = sum_c a_c f_c + b_c g_c per problem (f,g in registers)
    float cost = 0.f;
    if (p2) cost = Pa[c] * fv + Pb[c] * gv;
    float v = wave_red_sum(cost);
    if ((t & 63) == 0) red[t >> 6] = v;
    __syncthreads();
    if (t < 3) {
        float s = red[t * 4] + red[t * 4 + 1] + red[t * 4 + 2] + red[t * 4 + 3];
        atomicAdd(&wsacc[(w * 3 + t) >> 8], s);
    }
}

// ---------------- finalize ----------------
__global__ void k_final(const float* __restrict__ wsacc, const float* __restrict__ lvr_p,
                        const float* __restrict__ lvt_p, float* __restrict__ out) {
    float recon = wsacc[3] * (1.f / (256.f * 4096.f));
    float ot0 = wsacc[0] * (1.f / 256.f);
    float ot1 = wsacc[1] * (1.f / 256.f);
    float ot2 = wsacc[2] * (1.f / 256.f);
    float topo = ot0 - 0.5f * ot1 - 0.5f * ot2;
    topo = topo > 0.f ? topo : 0.f;  // * TOPO_MULT (=1)
    float lvr = lvr_p[0], lvt = lvt_p[0];
    out[0] = 0.5f * __expf(-lvr) * recon + 0.5f * lvr +
             0.5f * __expf(-lvt) * topo + 0.5f * lvt;
    out[1] = recon;
    out[2] = topo;
}

extern "C" void kernel_launch(void* const* d_in, const int* in_sizes, int n_in,
                              void* d_out, int out_size, void* d_ws, size_t ws_size,
                              hipStream_t stream) {
    const float* xo = (const float*)d_in[0];
    const float* xr = (const float*)d_in[1];
    const float* z  = (const float*)d_in[2];
    const float* lsl = (const float*)d_in[3];
    const float* lvr = (const float*)d_in[4];
    const float* lvt = (const float*)d_in[5];
    float* out = (float*)d_out;
    float* ws = (float*)d_ws;

    // ws layout (floats)
    float* acc = ws;                    // [0..2] ot sums, [3] recon sum, [4] sigma_orig
    float* xn  = ws + 64;               // 256*4096
    float* zn  = xn + 1048576;          // 256*256
    float* Do  = zn + 65536;
    float* Dl  = Do + 65536;
    float* Po  = Dl + 65536;
    float* Pl  = Po + 65536;
    float* ELo = Pl + 65536;
    float* ELl = ELo + 65536;
    float* Kh  = ELl + 65536;           // 65536 f16 = 32768 floats
    float* part = Kh + 32768;           // 16*65536 (big-gemm slabs)
    float* part2 = Po;                  // 4*65536 overlay: used before prep writes Po..ELl

    hipMemsetAsync(acc, 0, 64, stream);
    k_recon<<<512, 256, 0, stream>>>((const float4*)xo, (const float4*)xr, acc + 3);
    k_norm2<<<512, 256, 0, stream>>>((const float4*)xo, (const float4*)z,
                                     (float4*)xn, (float4*)zn);
    k_gemm_aat<<<dim3(4, 4, 20), 256, 0, stream>>>(xn, zn, part, part2);
    k_reduce_d<<<512, 256, 0, stream>>>(part, part2, Do, Dl);
    k_median<<<1, 1024, 0, stream>>>(Do, acc + 4);
    k_prep<<<256, 256, 0, stream>>>(Do, Dl, acc, lsl, Po, Pl, ELo, ELl, (f16*)Kh);
    k_sinkhorn<<<256, 1024, 0, stream>>>(Po, Pl, ELo, ELl, (const uint4*)Kh, acc);
    k_final<<<1, 1, 0, stream>>>(acc, lvr, lvt, out);
}

// Round 5
// 241.344 us; speedup vs baseline: 1.5680x; 1.1522x over previous
//
#include <hip/hip_runtime.h>
#include <hip/hip_fp16.h>

#define EPS 0.1f
#define SINK_ITERS 50
#define KSCALE_LN 9.0109133472f   /* 13*ln2 : K scaled by 2^13 into f16 normal range */
#define USTRIDE 264               /* U row stride in halfs (256 + 8 pad) */

typedef _Float16 f16;
typedef _Float16 f16x8 __attribute__((ext_vector_type(8)));
typedef float f32x4 __attribute__((ext_vector_type(4)));

#define PIN_U4(v) asm volatile("" : "+v"(v.x), "+v"(v.y), "+v"(v.z), "+v"(v.w))

__device__ __forceinline__ float wave_red_sum(float v) {
    #pragma unroll
    for (int o = 32; o; o >>= 1) v += __shfl_xor(v, o, 64);
    return v;
}

// ---------------- fused recon + row-normalize ----------------
// blocks 0..511: recon partial sums; 512..767: normalize xo rows; 768..1023: z rows.
__global__ __launch_bounds__(256) void k_pre(const float4* __restrict__ xo,
                                             const float4* __restrict__ xr,
                                             const float4* __restrict__ z,
                                             float4* __restrict__ xn,
                                             float4* __restrict__ zn,
                                             float* __restrict__ acc) {
    __shared__ float red[4];
    int b = blockIdx.x, t = threadIdx.x;
    if (b < 512) {
        int tid = b * 256 + t;
        float s = 0.f;
        for (int i = tid; i < 262144; i += 512 * 256) {
            float4 a = xo[i], r = xr[i];
            float d0 = r.x - a.x, d1 = r.y - a.y, d2 = r.z - a.z, d3 = r.w - a.w;
            s = fmaf(d0, d0, s); s = fmaf(d1, d1, s);
            s = fmaf(d2, d2, s); s = fmaf(d3, d3, s);
        }
        s = wave_red_sum(s);
        if ((t & 63) == 0) red[t >> 6] = s;
        __syncthreads();
        if (t == 0) atomicAdd(acc + 3, red[0] + red[1] + red[2] + red[3]);
    } else {
        int row = b - 512;
        const float4* src; float4* dst; int c4;
        if (row < 256) { src = xo + (size_t)row * 1024; dst = xn + (size_t)row * 1024; c4 = 1024; }
        else { src = z + (size_t)(row - 256) * 64; dst = zn + (size_t)(row - 256) * 64; c4 = 64; }
        float s = 0.f;
        for (int i = t; i < c4; i += 256) {
            float4 v = src[i];
            s = fmaf(v.x, v.x, s); s = fmaf(v.y, v.y, s);
            s = fmaf(v.z, v.z, s); s = fmaf(v.w, v.w, s);
        }
        s = wave_red_sum(s);
        if ((t & 63) == 0) red[t >> 6] = s;
        __syncthreads();
        float tot = red[0] + red[1] + red[2] + red[3];
        float rn = 1.f / sqrtf(fmaxf(tot, 1e-8f));
        for (int i = t; i < c4; i += 256) {
            float4 v = src[i];
            v.x *= rn; v.y *= rn; v.z *= rn; v.w *= rn;
            dst[i] = v;
        }
    }
}

// ---------------- merged GEMM: A@A^T k-slabs for xn (z<16) and zn (z>=16) ----------------
__global__ __launch_bounds__(256) void k_gemm_aat(const float* __restrict__ xn,
                                                  const float* __restrict__ zn,
                                                  float* __restrict__ part,
                                                  float* __restrict__ part2) {
    __shared__ float At[64][17], Bt[64][17];
    int zb = blockIdx.z;
    const float* A; int lda, k0, nk; float* out;
    if (zb < 16) { A = xn; lda = 4096; k0 = zb * 256; nk = 256; out = part + (size_t)zb * 65536; }
    else { A = zn; lda = 256; k0 = (zb - 16) * 64; nk = 64; out = part2 + (size_t)(zb - 16) * 65536; }
    int i0 = blockIdx.x * 64, j0 = blockIdx.y * 64;
    int t = threadIdx.x, tx = t & 15, ty = t >> 4;
    float acc[4][4] = {};
    for (int kc = 0; kc < nk; kc += 16) {
        __syncthreads();
        #pragma unroll
        for (int m = 0; m < 4; m++) {
            int idx = m * 256 + t;
            int kk = idx & 15, row = idx >> 4;
            At[row][kk] = A[(size_t)(i0 + row) * lda + k0 + kc + kk];
            Bt[row][kk] = A[(size_t)(j0 + row) * lda + k0 + kc + kk];
        }
        __syncthreads();
        #pragma unroll
        for (int kk = 0; kk < 16; kk++) {
            float a[4], b[4];
            #pragma unroll
            for (int m = 0; m < 4; m++) a[m] = At[ty * 4 + m][kk];
            #pragma unroll
            for (int n = 0; n < 4; n++) b[n] = Bt[tx * 4 + n][kk];
            #pragma unroll
            for (int m = 0; m < 4; m++)
                #pragma unroll
                for (int n = 0; n < 4; n++)
                    acc[m][n] = fmaf(a[m], b[n], acc[m][n]);
        }
    }
    #pragma unroll
    for (int m = 0; m < 4; m++) {
        float4 v = make_float4(acc[m][0], acc[m][1], acc[m][2], acc[m][3]);
        *(float4*)&out[(i0 + ty * 4 + m) * 256 + j0 + tx * 4] = v;
    }
}

// ---------------- Do = clip(1 - sum of 16 slabs, 0) ----------------
__global__ __launch_bounds__(256) void k_reduce_do(const float* __restrict__ part,
                                                   float* __restrict__ Do) {
    int e = blockIdx.x * 256 + threadIdx.x;
    float s = 0.f;
    for (int sl = 0; sl < 16; sl++) s += part[(size_t)sl * 65536 + e];
    Do[e] = fmaxf(1.f - s, 0.f);
}

// ---------------- exact median of 65536 non-negative floats ----------------
__device__ __forceinline__ int med_bin(float v) {
    int b = (int)(v * 4096.f);
    if (v < (float)b * (1.f / 4096.f)) b--;
    else if (v >= (float)(b + 1) * (1.f / 4096.f)) b++;
    if (b < 0) b = 0;
    if (b > 8191) b = 8191;
    return b;
}

__global__ __launch_bounds__(1024) void k_median(const float* __restrict__ D,
                                                 float* __restrict__ out_sigma) {
    __shared__ int hist[8192];
    __shared__ int redc[16];
    __shared__ int sh_bin[2];
    __shared__ int sh_tot;
    int t = threadIdx.x;
    unsigned r[64];
    #pragma unroll
    for (int i = 0; i < 64; i++) r[i] = __float_as_uint(D[t + i * 1024]);
    #pragma unroll
    for (int j = 0; j < 8; j++) hist[t + j * 1024] = 0;
    __syncthreads();
    #pragma unroll
    for (int i = 0; i < 64; i++)
        atomicAdd(&hist[med_bin(__uint_as_float(r[i]))], 1);
    __syncthreads();
    int s8 = 0;
    #pragma unroll
    for (int j = 0; j < 8; j++) s8 += hist[t * 8 + j];
    int inc = s8;
    #pragma unroll
    for (int o = 1; o < 64; o <<= 1) {
        int vv = __shfl_up(inc, o, 64);
        if ((t & 63) >= o) inc += vv;
    }
    if ((t & 63) == 63) redc[t >> 6] = inc;
    __syncthreads();
    int woff = 0;
    for (int wv = 0; wv < (t >> 6); wv++) woff += redc[wv];
    int excl = woff + inc - s8;
    for (int sel = 0; sel < 2; sel++) {
        int k = 32767 + sel;
        if (excl <= k && k < excl + s8) {
            int cum = excl, bfound = 8191;
            bool found = false;
            for (int j = 0; j < 8; j++) {
                int hc = hist[t * 8 + j];
                if (!found) {
                    if (cum + hc > k) { bfound = t * 8 + j; found = true; }
                    else cum += hc;
                }
            }
            sh_bin[sel] = bfound;
        }
    }
    __syncthreads();
    unsigned res[2];
    for (int sel = 0; sel < 2; sel++) {
        int k = 32767 + sel;
        int b = sh_bin[sel];
        unsigned lo = __float_as_uint((float)b * (1.f / 4096.f));
        unsigned hi = __float_as_uint((float)(b + 1) * (1.f / 4096.f));
        while (hi - lo > 1u) {
            unsigned mid = (lo + hi) >> 1;
            int c = 0;
            #pragma unroll
            for (int i = 0; i < 64; i++) c += (r[i] < mid) ? 1 : 0;
            #pragma unroll
            for (int o = 32; o; o >>= 1) c += __shfl_xor(c, o, 64);
            if ((t & 63) == 0) redc[t >> 6] = c;
            __syncthreads();
            if (t == 0) {
                int tot = 0;
                for (int wv = 0; wv < 16; wv++) tot += redc[wv];
                sh_tot = tot;
            }
            __syncthreads();
            if (sh_tot <= k) lo = mid; else hi = mid;
        }
        res[sel] = lo;
    }
    if (t == 0)
        out_sigma[0] = 0.5f * (__uint_as_float(res[0]) + __uint_as_float(res[1]));
}

// ---------------- prep: S, P, EPS*logP, f16 kernel K; Dl summed inline from part2 ----------------
__global__ __launch_bounds__(256) void k_prep(const float* __restrict__ Do,
                                              const float* __restrict__ part2,
                                              const float* __restrict__ wsacc,
                                              const float* __restrict__ lsl,
                                              float* __restrict__ Po, float* __restrict__ Pl,
                                              float* __restrict__ ELo, float* __restrict__ ELl,
                                              f16* __restrict__ Kh) {
    __shared__ float red[8];
    int i = blockIdx.x, j = threadIdx.x;
    int e = i * 256 + j;
    float sig_o = wsacc[4];
    if (sig_o == 0.f) sig_o = 1e-6f;
    float x = lsl[0];
    float sp = (x > 20.f) ? x : log1pf(__expf(x));
    float sig_l = sp + 1e-6f;
    float i2o = 1.f / (2.f * sig_o * sig_o);
    float i2l = 1.f / (2.f * sig_l * sig_l);
    float d_o = Do[e];
    float sD = part2[e] + part2[65536 + e] + part2[131072 + e] + part2[196608 + e];
    float d_l = fmaxf(1.f - sD, 0.f);
    float so = (i == j) ? 0.f : __expf(-d_o * d_o * i2o);
    float sl = (i == j) ? 0.f : __expf(-d_l * d_l * i2l);
    float wso = wave_red_sum(so);
    float wsl = wave_red_sum(sl);
    if ((j & 63) == 0) { red[j >> 6] = wso; red[4 + (j >> 6)] = wsl; }
    __syncthreads();
    float sum_o = red[0] + red[1] + red[2] + red[3];
    float sum_l = red[4] + red[5] + red[6] + red[7];
    float po = so / fmaxf(sum_o, 1e-8f);
    float pl = sl / fmaxf(sum_l, 1e-8f);
    Po[e] = po;
    Pl[e] = pl;
    ELo[e] = EPS * __logf(fmaxf(po, 1e-8f));
    ELl[e] = EPS * __logf(fmaxf(pl, 1e-8f));
    // K'[k=i][c=j] = exp(-C/eps) * 2^13; half index = ((k>>3)*256 + c)*8 + (k&7)
    float kv = __expf(-d_o * (1.f / EPS) + KSCALE_LN);
    Kh[(((i >> 3) * 256 + j) << 3) + (i & 7)] = (f16)kv;
}

// ---------------- Sinkhorn via MFMA: 48 WGs x 512 thr, 16 problems per WG ----------------
// Z[16][256] = U[16][256] x K[256][256] per half-step, K symmetric (B-transpose immune).
// B-frags (K) register-resident: wave wv owns cols [32wv,32wv+32) as 2 subtiles.
// U double-buffered in LDS (f16, row stride USTRIDE): ONE barrier per half-step.
// A layout [m=lane&15][k=quad*8+j] (m120-verified); C/D col=lane&15,row=quad*4+reg (m89).
__global__ __launch_bounds__(512, 2) void k_sinkhorn(const float* __restrict__ Po,
                                                     const float* __restrict__ Pl,
                                                     const float* __restrict__ ELo,
                                                     const float* __restrict__ ELl,
                                                     const uint4* __restrict__ Kq,
                                                     float* __restrict__ wsacc) {
    __shared__ __align__(16) f16 U[2][16 * USTRIDE];
    __shared__ float CW[8][16];
    int t = threadIdx.x;
    int lane = t & 63, wv = t >> 6;
    int m16 = lane & 15, quad = lane >> 4;
    int w = blockIdx.x;           // 48 WGs
    int s = w >> 4;               // sinkhorn instance 0..2
    int ibase = (w & 15) * 16;    // batch-row base for this WG's 16 problems

    // B-fragments: K[k=kc*32+quad*8+j][c=32wv+st*16+m16], from Kh's octet layout
    uint4 bf0[8], bf1[8];
    int cA = 32 * wv + m16, cB = cA + 16;
    #pragma unroll
    for (int kc = 0; kc < 8; kc++) {
        bf0[kc] = Kq[(kc * 4 + quad) * 256 + cA];
        bf1[kc] = Kq[(kc * 4 + quad) * 256 + cB];
    }
    #pragma unroll
    for (int kc = 0; kc < 8; kc++) { PIN_U4(bf0[kc]); PIN_U4(bf1[kc]); }

    // per-lane EL constants for its 8 (p,c) outputs
    const float* ELa_b = (s == 1 ? ELl : ELo);
    const float* ELb_b = (s == 2 ? ELo : ELl);
    float ela[2][4], elb[2][4];
    #pragma unroll
    for (int reg = 0; reg < 4; reg++) {
        int i = ibase + quad * 4 + reg;
        ela[0][reg] = ELa_b[i * 256 + cA] + EPS * KSCALE_LN;
        ela[1][reg] = ELa_b[i * 256 + cB] + EPS * KSCALE_LN;
        elb[0][reg] = ELb_b[i * 256 + cA] + EPS * KSCALE_LN;
        elb[1][reg] = ELb_b[i * 256 + cB] + EPS * KSCALE_LN;
    }

    // init U[0] = 1.0 (f16 0x3C00): 512 threads x 8 halfs = 16x256
    {
        int row = t >> 5, c0 = (t & 31) * 8;
        *(uint4*)&U[0][row * USTRIDE + c0] =
            make_uint4(0x3C003C00u, 0x3C003C00u, 0x3C003C00u, 0x3C003C00u);
    }
    __syncthreads();

    float df[2][4], dg[2][4];
    #pragma unroll
    for (int reg = 0; reg < 4; reg++) { df[0][reg] = df[1][reg] = dg[0][reg] = dg[1][reg] = 0.f; }

    for (int it = 0; it < 2 * SINK_ITERS; it++) {
        const f16* ub = &U[it & 1][0];
        f16* un = &U[(it + 1) & 1][0];
        f32x4 acc0 = {0.f, 0.f, 0.f, 0.f}, acc1 = {0.f, 0.f, 0.f, 0.f};
        #pragma unroll
        for (int kc = 0; kc < 8; kc++) {
            f16x8 a = *(const f16x8*)&ub[m16 * USTRIDE + kc * 32 + quad * 8];
            acc0 = __builtin_amdgcn_mfma_f32_16x16x32_f16(a, __builtin_bit_cast(f16x8, bf0[kc]),
                                                          acc0, 0, 0, 0);
            acc1 = __builtin_amdgcn_mfma_f32_16x16x32_f16(a, __builtin_bit_cast(f16x8, bf1[kc]),
                                                          acc1, 0, 0, 0);
        }
        // epilogue: d = el - eps*log z; u' = exp(d) -> other U buffer
        bool fstep = (it & 1);
        #pragma unroll
        for (int reg = 0; reg < 4; reg++) {
            int p = quad * 4 + reg;
            float z0 = acc0[reg], z1 = acc1[reg];
            float e0 = fstep ? ela[0][reg] : elb[0][reg];
            float e1 = fstep ? ela[1][reg] : elb[1][reg];
            float d0 = e0 - EPS * __logf(z0);
            float d1 = e1 - EPS * __logf(z1);
            if (fstep) { df[0][reg] = d0; df[1][reg] = d1; }
            else       { dg[0][reg] = d0; dg[1][reg] = d1; }
            un[p * USTRIDE + cA] = (f16)__expf(d0);
            un[p * USTRIDE + cB] = (f16)__expf(d1);
        }
        __syncthreads();
    }

    // cost epilogue: per problem r=ibase+p: sum_c Pa[c]*f[c] + Pb[c]*g[c]
    const float* PaB = (s == 1 ? Pl : Po);
    const float* PbB = (s == 2 ? Po : Pl);
    float cs[4];
    #pragma unroll
    for (int reg = 0; reg < 4; reg++) {
        int i = ibase + quad * 4 + reg;
        cs[reg] = PaB[i * 256 + cA] * df[0][reg] + PbB[i * 256 + cA] * dg[0][reg] +
                  PaB[i * 256 + cB] * df[1][reg] + PbB[i * 256 + cB] * dg[1][reg];
    }
    #pragma unroll
    for (int o = 1; o < 16; o <<= 1) {
        #pragma unroll
        for (int reg = 0; reg < 4; reg++) cs[reg] += __shfl_xor(cs[reg], o, 64);
    }
    if (m16 == 0) {
        #pragma unroll
        for (int reg = 0; reg < 4; reg++) CW[wv][quad * 4 + reg] = cs[reg];
    }
    __syncthreads();
    if (wv == 0) {
        float v = 0.f;
        if (lane < 16) {
            #pragma unroll
            for (int w2 = 0; w2 < 8; w2++) v += CW[w2][lane];
        }
        v = wave_red_sum(v);
        if (lane == 0) atomicAdd(&wsacc[s], v);
    }
}

// ---------------- finalize ----------------
__global__ void k_final(const float* __restrict__ wsacc, const float* __restrict__ lvr_p,
                        const float* __restrict__ lvt_p, float* __restrict__ out) {
    float recon = wsacc[3] * (1.f / (256.f * 4096.f));
    float ot0 = wsacc[0] * (1.f / 256.f);
    float ot1 = wsacc[1] * (1.f / 256.f);
    float ot2 = wsacc[2] * (1.f / 256.f);
    float topo = ot0 - 0.5f * ot1 - 0.5f * ot2;
    topo = topo > 0.f ? topo : 0.f;  // * TOPO_MULT (=1)
    float lvr = lvr_p[0], lvt = lvt_p[0];
    out[0] = 0.5f * __expf(-lvr) * recon + 0.5f * lvr +
             0.5f * __expf(-lvt) * topo + 0.5f * lvt;
    out[1] = recon;
    out[2] = topo;
}

extern "C" void kernel_launch(void* const* d_in, const int* in_sizes, int n_in,
                              void* d_out, int out_size, void* d_ws, size_t ws_size,
                              hipStream_t stream) {
    const float* xo = (const float*)d_in[0];
    const float* xr = (const float*)d_in[1];
    const float* z  = (const float*)d_in[2];
    const float* lsl = (const float*)d_in[3];
    const float* lvr = (const float*)d_in[4];
    const float* lvt = (const float*)d_in[5];
    float* out = (float*)d_out;
    float* ws = (float*)d_ws;

    // ws layout (floats)
    float* acc = ws;                    // [0..2] ot sums, [3] recon sum, [4] sigma_orig
    float* xn  = ws + 64;               // 256*4096
    float* zn  = xn + 1048576;          // 256*256
    float* Do  = zn + 65536;
    float* Po  = Do + 65536;
    float* Pl  = Po + 65536;
    float* ELo = Pl + 65536;
    float* ELl = ELo + 65536;
    float* Kh  = ELl + 65536;           // 65536 f16 = 32768 floats
    float* part = Kh + 32768;           // 16*65536 (xn-gemm slabs)
    float* part2 = Po;                  // 4*65536 overlay: consumed by prep before it writes Po..ELl

    hipMemsetAsync(acc, 0, 64, stream);
    k_pre<<<1024, 256, 0, stream>>>((const float4*)xo, (const float4*)xr, (const float4*)z,
                                    (float4*)xn, (float4*)zn, acc);
    k_gemm_aat<<<dim3(4, 4, 20), 256, 0, stream>>>(xn, zn, part, part2);
    k_reduce_do<<<256, 256, 0, stream>>>(part, Do);
    k_median<<<1, 1024, 0, stream>>>(Do, acc + 4);
    k_prep<<<256, 256, 0, stream>>>(Do, part2, acc, lsl, Po, Pl, ELo, ELl, (f16*)Kh);
    k_sinkhorn<<<48, 512, 0, stream>>>(Po, Pl, ELo, ELl, (const uint4*)Kh, acc);
    k_final<<<1, 1, 0, stream>>>(acc, lvr, lvt, out);
}

// Round 6
// 223.131 us; speedup vs baseline: 1.6959x; 1.0816x over previous
//
#include <hip/hip_runtime.h>
#include <hip/hip_fp16.h>

#define EPS 0.1f
#define SINK_ITERS 50
#define KSCALE_LN 9.0109133472f   /* 13*ln2 : K scaled by 2^13 into f16 normal range */
#define USTRIDE 272               /* U row stride in halfs: 136 dwords == 8 (mod 32) -> 2/bank */

typedef _Float16 f16;
typedef _Float16 f16x4 __attribute__((ext_vector_type(4)));
typedef _Float16 f16x8 __attribute__((ext_vector_type(8)));
typedef float f32x4 __attribute__((ext_vector_type(4)));

#define PIN_U4(v) asm volatile("" : "+v"(v.x), "+v"(v.y), "+v"(v.z), "+v"(v.w))

__device__ __forceinline__ float wave_red_sum(float v) {
    #pragma unroll
    for (int o = 32; o; o >>= 1) v += __shfl_xor(v, o, 64);
    return v;
}

// ---------------- fused recon + row-normalize (outputs f16) ----------------
// blocks 0..511: recon partials; 512..767: xo rows -> xh; 768..1023: z rows -> zh.
__global__ __launch_bounds__(256) void k_pre(const float4* __restrict__ xo,
                                             const float4* __restrict__ xr,
                                             const float4* __restrict__ z,
                                             f16x4* __restrict__ xh,
                                             f16x4* __restrict__ zh,
                                             float* __restrict__ acc) {
    __shared__ float red[4];
    int b = blockIdx.x, t = threadIdx.x;
    if (b < 512) {
        int tid = b * 256 + t;
        float s = 0.f;
        for (int i = tid; i < 262144; i += 512 * 256) {
            float4 a = xo[i], r = xr[i];
            float d0 = r.x - a.x, d1 = r.y - a.y, d2 = r.z - a.z, d3 = r.w - a.w;
            s = fmaf(d0, d0, s); s = fmaf(d1, d1, s);
            s = fmaf(d2, d2, s); s = fmaf(d3, d3, s);
        }
        s = wave_red_sum(s);
        if ((t & 63) == 0) red[t >> 6] = s;
        __syncthreads();
        if (t == 0) atomicAdd(acc + 3, red[0] + red[1] + red[2] + red[3]);
    } else {
        int row = b - 512;
        const float4* src; f16x4* dst; int c4;
        if (row < 256) { src = xo + (size_t)row * 1024; dst = xh + (size_t)row * 1024; c4 = 1024; }
        else { src = z + (size_t)(row - 256) * 64; dst = zh + (size_t)(row - 256) * 64; c4 = 64; }
        float s = 0.f;
        for (int i = t; i < c4; i += 256) {
            float4 v = src[i];
            s = fmaf(v.x, v.x, s); s = fmaf(v.y, v.y, s);
            s = fmaf(v.z, v.z, s); s = fmaf(v.w, v.w, s);
        }
        s = wave_red_sum(s);
        if ((t & 63) == 0) red[t >> 6] = s;
        __syncthreads();
        float tot = red[0] + red[1] + red[2] + red[3];
        float rn = 1.f / sqrtf(fmaxf(tot, 1e-8f));
        for (int i = t; i < c4; i += 256) {
            float4 v = src[i];
            f16x4 h;
            h[0] = (f16)(v.x * rn); h[1] = (f16)(v.y * rn);
            h[2] = (f16)(v.z * rn); h[3] = (f16)(v.w * rn);
            dst[i] = h;
        }
    }
}

// ---------------- f16 MFMA GEMM: X@X^T k-slabs, xh (zb<16) and zh (zb>=16) ----------------
// grid (4,4,20), block 256 (4 waves). 64x64 tile; wave wv does 16-row strip x 64 cols.
__global__ __launch_bounds__(256) void k_gemm_f16(const uint4* __restrict__ xh,
                                                  const uint4* __restrict__ zh,
                                                  float* __restrict__ part,
                                                  float* __restrict__ part2) {
    __shared__ __align__(16) f16 Ai[64 * 40], Bj[64 * 40];
    int zb = blockIdx.z;
    const uint4* X; int lda8, k0, nchunk; float* out;
    if (zb < 16) { X = xh; lda8 = 512; k0 = zb * 256; nchunk = 8; out = part + (size_t)zb * 65536; }
    else { X = zh; lda8 = 32; k0 = (zb - 16) * 64; nchunk = 2; out = part2 + (size_t)(zb - 16) * 65536; }
    int i0 = blockIdx.x * 64, j0 = blockIdx.y * 64;
    int t = threadIdx.x, lane = t & 63, wv = t >> 6;
    int m16 = lane & 15, quad = lane >> 4;
    int r = t >> 2, ko = (t & 3) * 8;
    f32x4 acc[4] = {};
    for (int ch = 0; ch < nchunk; ch++) {
        int kb8 = (k0 + ch * 32) >> 3;
        uint4 va = X[(size_t)(i0 + r) * lda8 + kb8 + (t & 3)];
        uint4 vb = X[(size_t)(j0 + r) * lda8 + kb8 + (t & 3)];
        __syncthreads();
        *(uint4*)&Ai[r * 40 + ko] = va;
        *(uint4*)&Bj[r * 40 + ko] = vb;
        __syncthreads();
        f16x8 a = *(const f16x8*)&Ai[(wv * 16 + m16) * 40 + quad * 8];
        #pragma unroll
        for (int st = 0; st < 4; st++) {
            f16x8 bfr = *(const f16x8*)&Bj[(st * 16 + m16) * 40 + quad * 8];
            acc[st] = __builtin_amdgcn_mfma_f32_16x16x32_f16(a, bfr, acc[st], 0, 0, 0);
        }
    }
    #pragma unroll
    for (int st = 0; st < 4; st++)
        #pragma unroll
        for (int reg = 0; reg < 4; reg++)
            out[(i0 + wv * 16 + quad * 4 + reg) * 256 + j0 + st * 16 + m16] = acc[st][reg];
}

// ---------------- Do = clip(1 - sum of 16 slabs, 0) ----------------
__global__ __launch_bounds__(256) void k_reduce_do(const float* __restrict__ part,
                                                   float* __restrict__ Do) {
    int e = blockIdx.x * 256 + threadIdx.x;
    float s = 0.f;
    for (int sl = 0; sl < 16; sl++) s += part[(size_t)sl * 65536 + e];
    Do[e] = fmaxf(1.f - s, 0.f);
}

// ---------------- exact median of 65536 non-negative floats ----------------
__device__ __forceinline__ int med_bin(float v) {
    int b = (int)(v * 4096.f);
    if (v < (float)b * (1.f / 4096.f)) b--;
    else if (v >= (float)(b + 1) * (1.f / 4096.f)) b++;
    if (b < 0) b = 0;
    if (b > 8191) b = 8191;
    return b;
}

__global__ __launch_bounds__(1024) void k_median(const float* __restrict__ D,
                                                 float* __restrict__ out_sigma) {
    __shared__ int hist[8192];
    __shared__ int redc[16];
    __shared__ int sh_bin[2];
    __shared__ int sh_tot;
    int t = threadIdx.x;
    unsigned r[64];
    #pragma unroll
    for (int i = 0; i < 64; i++) r[i] = __float_as_uint(D[t + i * 1024]);
    #pragma unroll
    for (int j = 0; j < 8; j++) hist[t + j * 1024] = 0;
    __syncthreads();
    #pragma unroll
    for (int i = 0; i < 64; i++)
        atomicAdd(&hist[med_bin(__uint_as_float(r[i]))], 1);
    __syncthreads();
    int s8 = 0;
    #pragma unroll
    for (int j = 0; j < 8; j++) s8 += hist[t * 8 + j];
    int inc = s8;
    #pragma unroll
    for (int o = 1; o < 64; o <<= 1) {
        int vv = __shfl_up(inc, o, 64);
        if ((t & 63) >= o) inc += vv;
    }
    if ((t & 63) == 63) redc[t >> 6] = inc;
    __syncthreads();
    int woff = 0;
    for (int wv = 0; wv < (t >> 6); wv++) woff += redc[wv];
    int excl = woff + inc - s8;
    for (int sel = 0; sel < 2; sel++) {
        int k = 32767 + sel;
        if (excl <= k && k < excl + s8) {
            int cum = excl, bfound = 8191;
            bool found = false;
            for (int j = 0; j < 8; j++) {
                int hc = hist[t * 8 + j];
                if (!found) {
                    if (cum + hc > k) { bfound = t * 8 + j; found = true; }
                    else cum += hc;
                }
            }
            sh_bin[sel] = bfound;
        }
    }
    __syncthreads();
    unsigned res[2];
    for (int sel = 0; sel < 2; sel++) {
        int k = 32767 + sel;
        int b = sh_bin[sel];
        unsigned lo = __float_as_uint((float)b * (1.f / 4096.f));
        unsigned hi = __float_as_uint((float)(b + 1) * (1.f / 4096.f));
        while (hi - lo > 1u) {
            unsigned mid = (lo + hi) >> 1;
            int c = 0;
            #pragma unroll
            for (int i = 0; i < 64; i++) c += (r[i] < mid) ? 1 : 0;
            #pragma unroll
            for (int o = 32; o; o >>= 1) c += __shfl_xor(c, o, 64);
            if ((t & 63) == 0) redc[t >> 6] = c;
            __syncthreads();
            if (t == 0) {
                int tot = 0;
                for (int wv = 0; wv < 16; wv++) tot += redc[wv];
                sh_tot = tot;
            }
            __syncthreads();
            if (sh_tot <= k) lo = mid; else hi = mid;
        }
        res[sel] = lo;
    }
    if (t == 0)
        out_sigma[0] = 0.5f * (__uint_as_float(res[0]) + __uint_as_float(res[1]));
}

// ---------------- prep: S, P, EPS*logP, f16 kernel K; Dl summed inline from part2 ----------------
__global__ __launch_bounds__(256) void k_prep(const float* __restrict__ Do,
                                              const float* __restrict__ part2,
                                              const float* __restrict__ wsacc,
                                              const float* __restrict__ lsl,
                                              float* __restrict__ Po, float* __restrict__ Pl,
                                              float* __restrict__ ELo, float* __restrict__ ELl,
                                              f16* __restrict__ Kh) {
    __shared__ float red[8];
    int i = blockIdx.x, j = threadIdx.x;
    int e = i * 256 + j;
    float sig_o = wsacc[4];
    if (sig_o == 0.f) sig_o = 1e-6f;
    float x = lsl[0];
    float sp = (x > 20.f) ? x : log1pf(__expf(x));
    float sig_l = sp + 1e-6f;
    float i2o = 1.f / (2.f * sig_o * sig_o);
    float i2l = 1.f / (2.f * sig_l * sig_l);
    float d_o = Do[e];
    float sD = part2[e] + part2[65536 + e] + part2[131072 + e] + part2[196608 + e];
    float d_l = fmaxf(1.f - sD, 0.f);
    float so = (i == j) ? 0.f : __expf(-d_o * d_o * i2o);
    float sl = (i == j) ? 0.f : __expf(-d_l * d_l * i2l);
    float wso = wave_red_sum(so);
    float wsl = wave_red_sum(sl);
    if ((j & 63) == 0) { red[j >> 6] = wso; red[4 + (j >> 6)] = wsl; }
    __syncthreads();
    float sum_o = red[0] + red[1] + red[2] + red[3];
    float sum_l = red[4] + red[5] + red[6] + red[7];
    float po = so / fmaxf(sum_o, 1e-8f);
    float pl = sl / fmaxf(sum_l, 1e-8f);
    Po[e] = po;
    Pl[e] = pl;
    ELo[e] = EPS * __logf(fmaxf(po, 1e-8f));
    ELl[e] = EPS * __logf(fmaxf(pl, 1e-8f));
    // K'[k=i][c=j] = exp(-C/eps) * 2^13; half index = ((k>>3)*256 + c)*8 + (k&7)
    float kv = __expf(-d_o * (1.f / EPS) + KSCALE_LN);
    Kh[(((i >> 3) * 256 + j) << 3) + (i & 7)] = (f16)kv;
}

// ---------------- Sinkhorn via MFMA: 192 WGs x 512 thr, 4 problems per WG ----------------
// M-tile underfilled on purpose (rows 0..3 valid): WG count = 768/4 covers 192 CUs.
// U rows replicated on read via (m16&3) -> 4-lane broadcast; USTRIDE=272 halfs
// (136 dw == 8 mod 32) -> exactly 2 distinct dwords/bank per b128 read (free).
// Epilogue (log/exp/writes) only on quad-0 lanes (C/D rows 0..3).
__global__ __launch_bounds__(512, 2) void k_sinkhorn(const float* __restrict__ Po,
                                                     const float* __restrict__ Pl,
                                                     const float* __restrict__ ELo,
                                                     const float* __restrict__ ELl,
                                                     const uint4* __restrict__ Kq,
                                                     float* __restrict__ wsacc) {
    __shared__ __align__(16) f16 U[2][4 * USTRIDE];
    __shared__ float CW[8][4];
    int t = threadIdx.x;
    int lane = t & 63, wv = t >> 6;
    int m16 = lane & 15, quad = lane >> 4;
    int w = blockIdx.x;           // 192 WGs
    int s = w >> 6;               // sinkhorn instance 0..2
    int ibase = (w & 63) * 4;     // 4 problems per WG

    // B-fragments: K[k=kc*32+quad*8+j][c], register-resident
    uint4 bf0[8], bf1[8];
    int cA = 32 * wv + m16, cB = cA + 16;
    #pragma unroll
    for (int kc = 0; kc < 8; kc++) {
        bf0[kc] = Kq[(kc * 4 + quad) * 256 + cA];
        bf1[kc] = Kq[(kc * 4 + quad) * 256 + cB];
    }
    #pragma unroll
    for (int kc = 0; kc < 8; kc++) { PIN_U4(bf0[kc]); PIN_U4(bf1[kc]); }

    // EL constants only where outputs live (quad 0, rows 0..3)
    const float* ELa_b = (s == 1 ? ELl : ELo);
    const float* ELb_b = (s == 2 ? ELo : ELl);
    float ela[2][4] = {}, elb[2][4] = {};
    if (quad == 0) {
        #pragma unroll
        for (int reg = 0; reg < 4; reg++) {
            int i = ibase + reg;
            ela[0][reg] = ELa_b[i * 256 + cA] + EPS * KSCALE_LN;
            ela[1][reg] = ELa_b[i * 256 + cB] + EPS * KSCALE_LN;
            elb[0][reg] = ELb_b[i * 256 + cA] + EPS * KSCALE_LN;
            elb[1][reg] = ELb_b[i * 256 + cB] + EPS * KSCALE_LN;
        }
    }

    // init U[0] = 1.0 (f16 0x3C00): 4*272 halfs = 136 uint4
    if (t < 136)
        *(uint4*)&U[0][t * 8] =
            make_uint4(0x3C003C00u, 0x3C003C00u, 0x3C003C00u, 0x3C003C00u);
    __syncthreads();

    float df[2][4] = {}, dg[2][4] = {};
    for (int it = 0; it < 2 * SINK_ITERS; it++) {
        const f16* ub = &U[it & 1][0];
        f16* un = &U[(it + 1) & 1][0];
        f32x4 acc0 = {0.f, 0.f, 0.f, 0.f}, acc1 = {0.f, 0.f, 0.f, 0.f};
        #pragma unroll
        for (int kc = 0; kc < 8; kc++) {
            f16x8 a = *(const f16x8*)&ub[(m16 & 3) * USTRIDE + kc * 32 + quad * 8];
            acc0 = __builtin_amdgcn_mfma_f32_16x16x32_f16(a, __builtin_bit_cast(f16x8, bf0[kc]),
                                                          acc0, 0, 0, 0);
            acc1 = __builtin_amdgcn_mfma_f32_16x16x32_f16(a, __builtin_bit_cast(f16x8, bf1[kc]),
                                                          acc1, 0, 0, 0);
        }
        bool fstep = (it & 1);
        if (quad == 0) {
            #pragma unroll
            for (int reg = 0; reg < 4; reg++) {
                float z0 = acc0[reg], z1 = acc1[reg];
                float e0 = fstep ? ela[0][reg] : elb[0][reg];
                float e1 = fstep ? ela[1][reg] : elb[1][reg];
                float d0 = e0 - EPS * __logf(z0);
                float d1 = e1 - EPS * __logf(z1);
                if (fstep) { df[0][reg] = d0; df[1][reg] = d1; }
                else       { dg[0][reg] = d0; dg[1][reg] = d1; }
                un[reg * USTRIDE + cA] = (f16)__expf(d0);
                un[reg * USTRIDE + cB] = (f16)__expf(d1);
            }
        }
        __syncthreads();
    }

    // cost epilogue: problem r=ibase+reg: sum_c Pa[c]*f[c] + Pb[c]*g[c]
    const float* PaB = (s == 1 ? Pl : Po);
    const float* PbB = (s == 2 ? Po : Pl);
    float cs[4] = {};
    if (quad == 0) {
        #pragma unroll
        for (int reg = 0; reg < 4; reg++) {
            int i = ibase + reg;
            cs[reg] = PaB[i * 256 + cA] * df[0][reg] + PbB[i * 256 + cA] * dg[0][reg] +
                      PaB[i * 256 + cB] * df[1][reg] + PbB[i * 256 + cB] * dg[1][reg];
        }
    }
    #pragma unroll
    for (int o = 1; o < 16; o <<= 1) {
        #pragma unroll
        for (int reg = 0; reg < 4; reg++) cs[reg] += __shfl_xor(cs[reg], o, 64);
    }
    if (lane == 0) {
        #pragma unroll
        for (int reg = 0; reg < 4; reg++) CW[wv][reg] = cs[reg];
    }
    __syncthreads();
    if (t == 0) {
        float v = 0.f;
        for (int w2 = 0; w2 < 8; w2++)
            v += CW[w2][0] + CW[w2][1] + CW[w2][2] + CW[w2][3];
        atomicAdd(&wsacc[s], v);
    }
}

// ---------------- finalize ----------------
__global__ void k_final(const float* __restrict__ wsacc, const float* __restrict__ lvr_p,
                        const float* __restrict__ lvt_p, float* __restrict__ out) {
    float recon = wsacc[3] * (1.f / (256.f * 4096.f));
    float ot0 = wsacc[0] * (1.f / 256.f);
    float ot1 = wsacc[1] * (1.f / 256.f);
    float ot2 = wsacc[2] * (1.f / 256.f);
    float topo = ot0 - 0.5f * ot1 - 0.5f * ot2;
    topo = topo > 0.f ? topo : 0.f;  // * TOPO_MULT (=1)
    float lvr = lvr_p[0], lvt = lvt_p[0];
    out[0] = 0.5f * __expf(-lvr) * recon + 0.5f * lvr +
             0.5f * __expf(-lvt) * topo + 0.5f * lvt;
    out[1] = recon;
    out[2] = topo;
}

extern "C" void kernel_launch(void* const* d_in, const int* in_sizes, int n_in,
                              void* d_out, int out_size, void* d_ws, size_t ws_size,
                              hipStream_t stream) {
    const float* xo = (const float*)d_in[0];
    const float* xr = (const float*)d_in[1];
    const float* z  = (const float*)d_in[2];
    const float* lsl = (const float*)d_in[3];
    const float* lvr = (const float*)d_in[4];
    const float* lvt = (const float*)d_in[5];
    float* out = (float*)d_out;
    float* ws = (float*)d_ws;

    // ws layout (floats)
    float* acc = ws;                    // [0..2] ot sums, [3] recon sum, [4] sigma_orig
    float* xh  = ws + 64;               // 256*4096 f16 = 524288 floats
    float* zh  = xh + 524288;           // 256*256 f16 = 32768 floats
    float* Do  = zh + 32768;
    float* Po  = Do + 65536;
    float* Pl  = Po + 65536;
    float* ELo = Pl + 65536;
    float* ELl = ELo + 65536;
    float* Kh  = ELl + 65536;           // 65536 f16 = 32768 floats
    float* part = Kh + 32768;           // 16*65536 (xh-gemm slabs)
    float* part2 = Po;                  // 4*65536 overlay: consumed by prep before it writes Po..ELl

    hipMemsetAsync(acc, 0, 64, stream);
    k_pre<<<1024, 256, 0, stream>>>((const float4*)xo, (const float4*)xr, (const float4*)z,
                                    (f16x4*)xh, (f16x4*)zh, acc);
    k_gemm_f16<<<dim3(4, 4, 20), 256, 0, stream>>>((const uint4*)xh, (const uint4*)zh,
                                                   part, part2);
    k_reduce_do<<<256, 256, 0, stream>>>(part, Do);
    k_median<<<1, 1024, 0, stream>>>(Do, acc + 4);
    k_prep<<<256, 256, 0, stream>>>(Do, part2, acc, lsl, Po, Pl, ELo, ELl, (f16*)Kh);
    k_sinkhorn<<<192, 512, 0, stream>>>(Po, Pl, ELo, ELl, (const uint4*)Kh, acc);
    k_final<<<1, 1, 0, stream>>>(acc, lvr, lvt, out);
}